// Round 1
// baseline (236.926 us; speedup 1.0000x reference)
//
#include <hip/hip_runtime.h>

#define N_TOK 3136
#define DH 64
#define NHEAD 2
#define CDIM 128
#define BATCH 8
#define ATT_SCALE 0.125f
#define LOG2E 1.4426950408889634f

typedef __attribute__((ext_vector_type(8))) short bf16x8;
typedef __attribute__((ext_vector_type(4))) float f32x4;
typedef __attribute__((ext_vector_type(4))) unsigned short u16x4;

__device__ __forceinline__ unsigned short f2bf(float f) {
  unsigned int u = __float_as_uint(f);
  u += 0x7fffu + ((u >> 16) & 1u);
  return (unsigned short)(u >> 16);
}

#define MFMA16(a, b, c) __builtin_amdgcn_mfma_f32_16x16x32_bf16(a, b, c, 0, 0, 0)

// ---------------------------------------------------------------------------
// Projection GEMM: out[m][n] = sum_k A[m][k] * W[n][k] + bias[n]
// M = 25088 (grid.x * 64), K = 128, N = 128.
// IN_F32:   A is f32 (convert to bf16 while staging) else A is bf16.
// OUT_SPLIT: write bf16 to [B][head][tok][64] (QKV), else f32 flat [M][128].
// ---------------------------------------------------------------------------
template<bool IN_F32, bool OUT_SPLIT>
__global__ __launch_bounds__(256)
void proj_gemm(const void* __restrict__ Ain, const float* __restrict__ W,
               const float* __restrict__ bias, void* __restrict__ Out)
{
  __shared__ __align__(16) unsigned short xs[64][136];
  __shared__ __align__(16) unsigned short wsh[128][136];
  const int tid = threadIdx.x;
  const int m0 = blockIdx.x * 64;
  const int w = tid >> 6, l = tid & 63;
  const int lk = l & 15, lg = l >> 4;

  // stage W (128x128 f32 -> bf16)
  {
    const float4* Wv = (const float4*)W;
#pragma unroll
    for (int i = 0; i < 16; ++i) {
      int f = tid + i * 256;
      float4 v = Wv[f];
      int row = f >> 5, col = (f & 31) << 2;
      u16x4 pk = { f2bf(v.x), f2bf(v.y), f2bf(v.z), f2bf(v.w) };
      *(u16x4*)&wsh[row][col] = pk;
    }
  }
  // stage A tile (64 rows x 128)
  if (IN_F32) {
    const float4* Xv = (const float4*)((const float*)Ain + (size_t)m0 * CDIM);
#pragma unroll
    for (int i = 0; i < 8; ++i) {
      int f = tid + i * 256;
      float4 v = Xv[f];
      int row = f >> 5, col = (f & 31) << 2;
      u16x4 pk = { f2bf(v.x), f2bf(v.y), f2bf(v.z), f2bf(v.w) };
      *(u16x4*)&xs[row][col] = pk;
    }
  } else {
    const bf16x8* Xv = (const bf16x8*)((const unsigned short*)Ain + (size_t)m0 * CDIM);
#pragma unroll
    for (int i = 0; i < 4; ++i) {
      int c = tid + i * 256;
      bf16x8 v = Xv[c];
      int row = c >> 4, col = (c & 15) << 3;
      *(bf16x8*)&xs[row][col] = v;
    }
  }
  __syncthreads();

  f32x4 acc[8];
#pragma unroll
  for (int nf = 0; nf < 8; ++nf) acc[nf] = (f32x4){0.f, 0.f, 0.f, 0.f};

#pragma unroll
  for (int kk = 0; kk < 4; ++kk) {
    bf16x8 a = *(const bf16x8*)&xs[w * 16 + lk][kk * 32 + 8 * lg];
#pragma unroll
    for (int nf = 0; nf < 8; ++nf) {
      bf16x8 b = *(const bf16x8*)&wsh[nf * 16 + lk][kk * 32 + 8 * lg];
      acc[nf] = MFMA16(a, b, acc[nf]);
    }
  }

#pragma unroll
  for (int reg = 0; reg < 4; ++reg) {
    int row = m0 + w * 16 + 4 * lg + reg;
    int bb = row / N_TOK;
    int tok = row - bb * N_TOK;
#pragma unroll
    for (int nf = 0; nf < 8; ++nf) {
      int col = nf * 16 + lk;
      float val = acc[nf][reg] + bias[col];
      if (OUT_SPLIT) {
        int head = nf >> 2;
        int d = col & 63;
        ((unsigned short*)Out)[((size_t)(bb * NHEAD + head) * N_TOK + tok) * DH + d] = f2bf(val);
      } else {
        ((float*)Out)[(size_t)row * CDIM + col] = val;
      }
    }
  }
}

// ---------------------------------------------------------------------------
// Flash attention: one WG (4 waves) per (batch, 64-row q-tile, head).
// Each wave owns 16 q rows. KVBLK=64, online softmax in fragments.
// ---------------------------------------------------------------------------
__global__ __launch_bounds__(256)
void attn_kernel(const unsigned short* __restrict__ q_ws,
                 const unsigned short* __restrict__ k_ws,
                 const unsigned short* __restrict__ v_ws,
                 const float* __restrict__ relpos,
                 unsigned short* __restrict__ attn_out)
{
  __shared__ __align__(16) unsigned short Ks[64][72];   // K tile [key][dim]
  __shared__ __align__(16) unsigned short Vts[64][72];  // V^T tile [dim][key]
  __shared__ __align__(16) unsigned short Ps[4][16][72];// per-wave P [qrow][key]

  const int b = blockIdx.x, qt = blockIdx.y, head = blockIdx.z;
  const int tid = threadIdx.x;
  const int w = tid >> 6, l = tid & 63;
  const int lk = l & 15, lg = l >> 4;

  const size_t bh = ((size_t)b * NHEAD + head) * N_TOK;
  const unsigned short* Qp = q_ws + (bh + (size_t)qt * 64) * DH;
  const unsigned short* Kp = k_ws + bh * DH;
  const unsigned short* Vp = v_ws + bh * DH;

  // Q fragments held in registers for the whole kv loop.
  // A-frag: row = lk (within wave's 16-row block), k = ks*32 + 8*lg + e
  bf16x8 qf[2];
  {
    const unsigned short* qrow = Qp + (size_t)(w * 16 + lk) * DH + 8 * lg;
    qf[0] = *(const bf16x8*)qrow;
    qf[1] = *(const bf16x8*)(qrow + 32);
  }

  const int qrow0 = qt * 64 + w * 16;
  const float* rp_row[4];
#pragma unroll
  for (int r = 0; r < 4; ++r)
    rp_row[r] = relpos + (size_t)head * N_TOK * N_TOK +
                (size_t)(qrow0 + 4 * lg + r) * N_TOK + lk;

  float m_run[4], l_run[4];
  f32x4 acc[4];
#pragma unroll
  for (int r = 0; r < 4; ++r) { m_run[r] = -1e30f; l_run[r] = 0.f; }
#pragma unroll
  for (int nf = 0; nf < 4; ++nf) acc[nf] = (f32x4){0.f, 0.f, 0.f, 0.f};

  for (int kt = 0; kt < N_TOK / 64; ++kt) {
    __syncthreads();  // previous tile fully consumed
    // stage K tile: 512 chunks of 8 bf16; row = c>>3, d0 = (c&7)*8
#pragma unroll
    for (int i = 0; i < 2; ++i) {
      int c = tid + i * 256;
      int row = c >> 3, d0 = (c & 7) << 3;
      bf16x8 v = *(const bf16x8*)(Kp + (size_t)(kt * 64 + row) * DH + d0);
      *(bf16x8*)&Ks[row][d0] = v;
    }
    // stage V transposed: key = c&63, d0 = (c>>6)*8 (bank-balanced scatter)
#pragma unroll
    for (int i = 0; i < 2; ++i) {
      int c = tid + i * 256;
      int key = c & 63, d0 = (c >> 6) << 3;
      bf16x8 v = *(const bf16x8*)(Vp + (size_t)(kt * 64 + key) * DH + d0);
#pragma unroll
      for (int j = 0; j < 8; ++j) Vts[d0 + j][key] = (unsigned short)v[j];
    }
    // relpos for this lane's 16 (row,col) fragment positions (overlaps staging)
    float rp[4][4];
#pragma unroll
    for (int r = 0; r < 4; ++r) {
      const float* rr = rp_row[r] + kt * 64;
#pragma unroll
      for (int ct = 0; ct < 4; ++ct) rp[ct][r] = rr[ct * 16];
    }
    __syncthreads();  // staging visible

    // S = Q K^T  (C layout: col = lk, row = 4*lg + reg)
    f32x4 s[4];
#pragma unroll
    for (int ct = 0; ct < 4; ++ct) s[ct] = (f32x4){0.f, 0.f, 0.f, 0.f};
#pragma unroll
    for (int ks = 0; ks < 2; ++ks) {
#pragma unroll
      for (int ct = 0; ct < 4; ++ct) {
        bf16x8 kb = *(const bf16x8*)&Ks[ct * 16 + lk][ks * 32 + 8 * lg];
        s[ct] = MFMA16(qf[ks], kb, s[ct]);
      }
    }
#pragma unroll
    for (int ct = 0; ct < 4; ++ct)
#pragma unroll
      for (int r = 0; r < 4; ++r)
        s[ct][r] = s[ct][r] * ATT_SCALE + rp[ct][r];

    // row max (16-lane butterfly within col groups)
    float tmax[4];
#pragma unroll
    for (int r = 0; r < 4; ++r)
      tmax[r] = fmaxf(fmaxf(s[0][r], s[1][r]), fmaxf(s[2][r], s[3][r]));
#pragma unroll
    for (int m = 1; m <= 8; m <<= 1)
#pragma unroll
      for (int r = 0; r < 4; ++r)
        tmax[r] = fmaxf(tmax[r], __shfl_xor(tmax[r], m, 64));

    float corr[4];
#pragma unroll
    for (int r = 0; r < 4; ++r) {
      float mn = fmaxf(m_run[r], tmax[r]);
      corr[r] = exp2f((m_run[r] - mn) * LOG2E);
      m_run[r] = mn;
    }
    float psum[4] = {0.f, 0.f, 0.f, 0.f};
#pragma unroll
    for (int ct = 0; ct < 4; ++ct)
#pragma unroll
      for (int r = 0; r < 4; ++r) {
        float p = exp2f((s[ct][r] - m_run[r]) * LOG2E);
        s[ct][r] = p;
        psum[r] += p;
      }
#pragma unroll
    for (int m = 1; m <= 8; m <<= 1)
#pragma unroll
      for (int r = 0; r < 4; ++r) psum[r] += __shfl_xor(psum[r], m, 64);
#pragma unroll
    for (int r = 0; r < 4; ++r) l_run[r] = l_run[r] * corr[r] + psum[r];
#pragma unroll
    for (int nf = 0; nf < 4; ++nf)
#pragma unroll
      for (int r = 0; r < 4; ++r) acc[nf][r] *= corr[r];

    // P -> LDS (wave-private) to re-layout for PV A-operand
#pragma unroll
    for (int ct = 0; ct < 4; ++ct)
#pragma unroll
      for (int r = 0; r < 4; ++r)
        Ps[w][4 * lg + r][ct * 16 + lk] = f2bf(s[ct][r]);

    // O += P V   (A: row = lk, k = ks*32+8*lg+e; B from V^T rows)
#pragma unroll
    for (int ks = 0; ks < 2; ++ks) {
      bf16x8 pa = *(const bf16x8*)&Ps[w][lk][ks * 32 + 8 * lg];
#pragma unroll
      for (int nf = 0; nf < 4; ++nf) {
        bf16x8 vb = *(const bf16x8*)&Vts[nf * 16 + lk][ks * 32 + 8 * lg];
        acc[nf] = MFMA16(pa, vb, acc[nf]);
      }
    }
  }

  // epilogue: normalize and store bf16 [B][N][C]
#pragma unroll
  for (int r = 0; r < 4; ++r) {
    int tok = qrow0 + 4 * lg + r;
    float inv = 1.f / l_run[r];
#pragma unroll
    for (int nf = 0; nf < 4; ++nf) {
      attn_out[((size_t)b * N_TOK + tok) * CDIM + head * DH + nf * 16 + lk] =
          f2bf(acc[nf][r] * inv);
    }
  }
}

// ---------------------------------------------------------------------------
extern "C" void kernel_launch(void* const* d_in, const int* in_sizes, int n_in,
                              void* d_out, int out_size, void* d_ws, size_t ws_size,
                              hipStream_t stream) {
  (void)in_sizes; (void)n_in; (void)out_size; (void)ws_size;
  const float* x      = (const float*)d_in[0];
  const float* relpos = (const float*)d_in[3];
  const float* Wq = (const float*)d_in[4];  const float* bq = (const float*)d_in[5];
  const float* Wk = (const float*)d_in[6];  const float* bk = (const float*)d_in[7];
  const float* Wv = (const float*)d_in[8];  const float* bv = (const float*)d_in[9];
  const float* Wp = (const float*)d_in[10]; const float* bp = (const float*)d_in[11];

  const size_t QKV_ELEMS = (size_t)BATCH * NHEAD * N_TOK * DH;  // 3,211,264
  unsigned short* q_ws  = (unsigned short*)d_ws;
  unsigned short* k_ws  = q_ws + QKV_ELEMS;
  unsigned short* v_ws  = k_ws + QKV_ELEMS;
  unsigned short* ao_ws = v_ws + QKV_ELEMS;  // [B][N][C] bf16

  dim3 blk(256);
  const int MTILES = (BATCH * N_TOK) / 64;  // 392

  proj_gemm<true, true><<<MTILES, blk, 0, stream>>>((const void*)x, Wq, bq, (void*)q_ws);
  proj_gemm<true, true><<<MTILES, blk, 0, stream>>>((const void*)x, Wk, bk, (void*)k_ws);
  proj_gemm<true, true><<<MTILES, blk, 0, stream>>>((const void*)x, Wv, bv, (void*)v_ws);

  attn_kernel<<<dim3(BATCH, N_TOK / 64, NHEAD), blk, 0, stream>>>(
      q_ws, k_ws, v_ws, relpos, ao_ws);

  proj_gemm<false, false><<<MTILES, blk, 0, stream>>>((const void*)ao_ws, Wp, bp, d_out);
}

// Round 3
// 157.461 us; speedup vs baseline: 1.5047x; 1.5047x over previous
//
#include <hip/hip_runtime.h>

#define N_TOK 3136
#define DH 64
#define NHEAD 2
#define CDIM 128
#define BATCH 8
#define NT 49                      // kv tiles of 64
#define QK_SCALE 0.18033688011112f // 0.125 * log2(e)
#define LOG2E 1.4426950408889634f

typedef __attribute__((ext_vector_type(8))) short bf16x8;
typedef __attribute__((ext_vector_type(4))) float f32x4;
typedef __attribute__((ext_vector_type(4))) unsigned short u16x4;

__device__ __forceinline__ unsigned short f2bf(float f) {
  unsigned int u = __float_as_uint(f);
  u += 0x7fffu + ((u >> 16) & 1u);
  return (unsigned short)(u >> 16);
}

#define MFMA16(a, b, c) __builtin_amdgcn_mfma_f32_16x16x32_bf16(a, b, c, 0, 0, 0)

// ---------------------------------------------------------------------------
// Projection GEMM: out[m][n] = (sum_k A[m][k]*W[n][k] + bias[n]) * out_scale
// M = 25088, K = 128, N = 128.
// ---------------------------------------------------------------------------
template<bool IN_F32, bool OUT_SPLIT>
__global__ __launch_bounds__(256)
void proj_gemm(const void* __restrict__ Ain, const float* __restrict__ W,
               const float* __restrict__ bias, void* __restrict__ Out,
               float out_scale)
{
  __shared__ __align__(16) unsigned short xs[64][136];
  __shared__ __align__(16) unsigned short wsh[128][136];
  const int tid = threadIdx.x;
  const int m0 = blockIdx.x * 64;
  const int w = tid >> 6, l = tid & 63;
  const int lk = l & 15, lg = l >> 4;

  {
    const float4* Wv = (const float4*)W;
#pragma unroll
    for (int i = 0; i < 16; ++i) {
      int f = tid + i * 256;
      float4 v = Wv[f];
      int row = f >> 5, col = (f & 31) << 2;
      u16x4 pk = { f2bf(v.x), f2bf(v.y), f2bf(v.z), f2bf(v.w) };
      *(u16x4*)&wsh[row][col] = pk;
    }
  }
  if (IN_F32) {
    const float4* Xv = (const float4*)((const float*)Ain + (size_t)m0 * CDIM);
#pragma unroll
    for (int i = 0; i < 8; ++i) {
      int f = tid + i * 256;
      float4 v = Xv[f];
      int row = f >> 5, col = (f & 31) << 2;
      u16x4 pk = { f2bf(v.x), f2bf(v.y), f2bf(v.z), f2bf(v.w) };
      *(u16x4*)&xs[row][col] = pk;
    }
  } else {
    const bf16x8* Xv = (const bf16x8*)((const unsigned short*)Ain + (size_t)m0 * CDIM);
#pragma unroll
    for (int i = 0; i < 4; ++i) {
      int c = tid + i * 256;
      bf16x8 v = Xv[c];
      int row = c >> 4, col = (c & 15) << 3;
      *(bf16x8*)&xs[row][col] = v;
    }
  }
  __syncthreads();

  f32x4 acc[8];
#pragma unroll
  for (int nf = 0; nf < 8; ++nf) acc[nf] = (f32x4){0.f, 0.f, 0.f, 0.f};

#pragma unroll
  for (int kk = 0; kk < 4; ++kk) {
    bf16x8 a = *(const bf16x8*)&xs[w * 16 + lk][kk * 32 + 8 * lg];
#pragma unroll
    for (int nf = 0; nf < 8; ++nf) {
      bf16x8 b = *(const bf16x8*)&wsh[nf * 16 + lk][kk * 32 + 8 * lg];
      acc[nf] = MFMA16(a, b, acc[nf]);
    }
  }

#pragma unroll
  for (int reg = 0; reg < 4; ++reg) {
    int row = m0 + w * 16 + 4 * lg + reg;
    int bb = row / N_TOK;
    int tok = row - bb * N_TOK;
#pragma unroll
    for (int nf = 0; nf < 8; ++nf) {
      int col = nf * 16 + lk;
      float val = (acc[nf][reg] + bias[col]) * out_scale;
      if (OUT_SPLIT) {
        int head = nf >> 2;
        int d = col & 63;
        ((unsigned short*)Out)[((size_t)(bb * NHEAD + head) * N_TOK + tok) * DH + d] = f2bf(val);
      } else {
        ((float*)Out)[(size_t)row * CDIM + col] = val;
      }
    }
  }
}

// ---------------------------------------------------------------------------
// Flash attention, max-free softmax, reg-prefetch double buffering.
// One WG (4 waves) per (b, 64-q-tile, head). LDS layouts are R1-verified:
//   Ks  [64 key][72]  (K tile, row-padded)
//   Vts [64 d][72]    (V^T tile)
//   Ps  [4 w][16 q][72]  (per-wave P)
// ---------------------------------------------------------------------------
__global__ __launch_bounds__(256)
void attn_kernel(const unsigned short* __restrict__ q_ws,
                 const unsigned short* __restrict__ k_ws,
                 const unsigned short* __restrict__ v_ws,
                 const float* __restrict__ relpos,
                 unsigned short* __restrict__ attn_out)
{
  __shared__ __align__(16) unsigned short Ks[64][72];
  __shared__ __align__(16) unsigned short Vts[64][72];
  __shared__ __align__(16) unsigned short Ps[4][16][72];

  const int b = blockIdx.x, qt = blockIdx.y, head = blockIdx.z;
  const int tid = threadIdx.x;
  const int w = tid >> 6, l = tid & 63;
  const int lk = l & 15, lg = l >> 4;

  const size_t bh = ((size_t)b * NHEAD + head) * N_TOK;
  const unsigned short* Qp = q_ws + (bh + (size_t)qt * 64) * DH;
  const unsigned short* Kp = k_ws + bh * DH;
  const unsigned short* Vg = v_ws + bh * DH;

  // Q fragments (pre-scaled by 0.125*log2e in the projection)
  bf16x8 qf0, qf1;
  {
    const unsigned short* qrow = Qp + (size_t)(w * 16 + lk) * DH + 8 * lg;
    qf0 = *(const bf16x8*)qrow;
    qf1 = *(const bf16x8*)(qrow + 32);
  }

  // K staging mapping: chunk c in [0,512): key=c>>3, d0=(c&7)*8
  const int kr0 = tid >> 3;            // keys 0..31 (c0=tid), +32 for c1
  const int ku  = (tid & 7) << 3;
  const int gk0 = kr0 * DH + ku;
  const int gk1 = gk0 + 32 * DH;
  // V staging mapping: key=c&63, d0=(c>>6)*8
  const int vkey = tid & 63;
  const int vd0  = (tid >> 6) << 3;    // 8w for c0; +32 for c1
  const int gv0  = vkey * DH + vd0;
  const int gv1  = gv0 + 32;

  const int qrow0 = qt * 64 + w * 16;
  const float* rpb = relpos + (size_t)head * N_TOK * N_TOK +
                     (size_t)(qrow0 + 4 * lg) * N_TOK + lk;

  float l_run[4] = {0.f, 0.f, 0.f, 0.f};
  f32x4 acc[4];
#pragma unroll
  for (int nf = 0; nf < 4; ++nf) acc[nf] = (f32x4){0.f, 0.f, 0.f, 0.f};

  // prefetch tile 0 -> regs
  bf16x8 kpreA = *(const bf16x8*)(Kp + gk0);
  bf16x8 kpreB = *(const bf16x8*)(Kp + gk1);
  bf16x8 vpreA = *(const bf16x8*)(Vg + gv0);
  bf16x8 vpreB = *(const bf16x8*)(Vg + gv1);

  for (int kt = 0; kt < NT; ++kt) {
    // relpos for this tile (issued early; compiler waits at use)
    float rp[4][4];
#pragma unroll
    for (int r = 0; r < 4; ++r)
#pragma unroll
      for (int ct = 0; ct < 4; ++ct)
        rp[ct][r] = rpb[(size_t)r * N_TOK + kt * 64 + ct * 16];

    asm volatile("s_waitcnt lgkmcnt(0)" ::: "memory");
    __builtin_amdgcn_s_barrier();            // A: tile kt-1 fully consumed
    asm volatile("" ::: "memory");

    // store staged tile kt
    *(bf16x8*)&Ks[kr0][ku]      = kpreA;
    *(bf16x8*)&Ks[kr0 + 32][ku] = kpreB;
#pragma unroll
    for (int j = 0; j < 8; ++j) Vts[vd0 + j][vkey]      = (unsigned short)vpreA[j];
#pragma unroll
    for (int j = 0; j < 8; ++j) Vts[vd0 + 32 + j][vkey] = (unsigned short)vpreB[j];

    if (kt + 1 < NT) {                       // prefetch tile kt+1 -> regs
      const unsigned short* kn = Kp + (size_t)(kt + 1) * 64 * DH;
      const unsigned short* vn = Vg + (size_t)(kt + 1) * 64 * DH;
      kpreA = *(const bf16x8*)(kn + gk0);
      kpreB = *(const bf16x8*)(kn + gk1);
      vpreA = *(const bf16x8*)(vn + gv0);
      vpreB = *(const bf16x8*)(vn + gv1);
    }

    asm volatile("s_waitcnt lgkmcnt(0)" ::: "memory");
    __builtin_amdgcn_s_barrier();            // B: tile kt LDS visible
    asm volatile("" ::: "memory");

    // S = Q K^T  (C layout: col = key16 = lk, row = 4lg + r)
    f32x4 s[4];
#pragma unroll
    for (int ct = 0; ct < 4; ++ct) s[ct] = (f32x4){0.f, 0.f, 0.f, 0.f};
#pragma unroll
    for (int ct = 0; ct < 4; ++ct) {
      bf16x8 kb0 = *(const bf16x8*)&Ks[ct * 16 + lk][8 * lg];
      s[ct] = MFMA16(qf0, kb0, s[ct]);
      bf16x8 kb1 = *(const bf16x8*)&Ks[ct * 16 + lk][32 + 8 * lg];
      s[ct] = MFMA16(qf1, kb1, s[ct]);
    }

    // max-free softmax: p = 2^(s + rp*log2e); accumulate row partials
#pragma unroll
    for (int ct = 0; ct < 4; ++ct) {
      float p0 = __builtin_amdgcn_exp2f(fmaf(rp[ct][0], LOG2E, s[ct][0]));
      float p1 = __builtin_amdgcn_exp2f(fmaf(rp[ct][1], LOG2E, s[ct][1]));
      float p2 = __builtin_amdgcn_exp2f(fmaf(rp[ct][2], LOG2E, s[ct][2]));
      float p3 = __builtin_amdgcn_exp2f(fmaf(rp[ct][3], LOG2E, s[ct][3]));
      l_run[0] += p0; l_run[1] += p1; l_run[2] += p2; l_run[3] += p3;
      Ps[w][4 * lg + 0][ct * 16 + lk] = f2bf(p0);
      Ps[w][4 * lg + 1][ct * 16 + lk] = f2bf(p1);
      Ps[w][4 * lg + 2][ct * 16 + lk] = f2bf(p2);
      Ps[w][4 * lg + 3][ct * 16 + lk] = f2bf(p3);
    }

    // O += P V  (A: row=lk, k=keys; B: V^T rows = output dims)
    bf16x8 pa0 = *(const bf16x8*)&Ps[w][lk][8 * lg];
    bf16x8 pa1 = *(const bf16x8*)&Ps[w][lk][32 + 8 * lg];
#pragma unroll
    for (int nf = 0; nf < 4; ++nf) {
      bf16x8 vb0 = *(const bf16x8*)&Vts[nf * 16 + lk][8 * lg];
      acc[nf] = MFMA16(pa0, vb0, acc[nf]);
      bf16x8 vb1 = *(const bf16x8*)&Vts[nf * 16 + lk][32 + 8 * lg];
      acc[nf] = MFMA16(pa1, vb1, acc[nf]);
    }
  }

  // epilogue: reduce row sums across the 16 lk lanes, normalize, store bf16
#pragma unroll
  for (int m = 1; m <= 8; m <<= 1)
#pragma unroll
    for (int r = 0; r < 4; ++r)
      l_run[r] += __shfl_xor(l_run[r], m, 64);

#pragma unroll
  for (int r = 0; r < 4; ++r) {
    int tok = qrow0 + 4 * lg + r;
    float inv = 1.f / l_run[r];
#pragma unroll
    for (int nf = 0; nf < 4; ++nf) {
      attn_out[((size_t)b * N_TOK + tok) * CDIM + head * DH + nf * 16 + lk] =
          f2bf(acc[nf][r] * inv);
    }
  }
}

// ---------------------------------------------------------------------------
extern "C" void kernel_launch(void* const* d_in, const int* in_sizes, int n_in,
                              void* d_out, int out_size, void* d_ws, size_t ws_size,
                              hipStream_t stream) {
  (void)in_sizes; (void)n_in; (void)out_size; (void)ws_size;
  const float* x      = (const float*)d_in[0];
  const float* relpos = (const float*)d_in[3];
  const float* Wq = (const float*)d_in[4];  const float* bq = (const float*)d_in[5];
  const float* Wk = (const float*)d_in[6];  const float* bk = (const float*)d_in[7];
  const float* Wv = (const float*)d_in[8];  const float* bv = (const float*)d_in[9];
  const float* Wp = (const float*)d_in[10]; const float* bp = (const float*)d_in[11];

  const size_t QKV_ELEMS = (size_t)BATCH * NHEAD * N_TOK * DH;
  unsigned short* q_ws  = (unsigned short*)d_ws;
  unsigned short* k_ws  = q_ws + QKV_ELEMS;
  unsigned short* v_ws  = k_ws + QKV_ELEMS;
  unsigned short* ao_ws = v_ws + QKV_ELEMS;  // [B][N][C] bf16

  dim3 blk(256);
  const int MTILES = (BATCH * N_TOK) / 64;  // 392

  proj_gemm<true, true><<<MTILES, blk, 0, stream>>>((const void*)x, Wq, bq, (void*)q_ws, QK_SCALE);
  proj_gemm<true, true><<<MTILES, blk, 0, stream>>>((const void*)x, Wk, bk, (void*)k_ws, 1.f);
  proj_gemm<true, true><<<MTILES, blk, 0, stream>>>((const void*)x, Wv, bv, (void*)v_ws, 1.f);

  attn_kernel<<<dim3(BATCH, N_TOK / 64, NHEAD), blk, 0, stream>>>(
      q_ws, k_ws, v_ws, relpos, ao_ws);

  proj_gemm<false, false><<<MTILES, blk, 0, stream>>>((const void*)ao_ws, Wp, bp, d_out, 1.f);
}

// Round 5
// 145.286 us; speedup vs baseline: 1.6308x; 1.0838x over previous
//
#include <hip/hip_runtime.h>
#include <hip/hip_fp16.h>

#define N_TOK 3136
#define DH 64
#define NHEAD 2
#define CDIM 128
#define BATCH 8
#define NT 49                      // kv tiles of 64
#define QK_SCALE 0.18033688011112f // 0.125 * log2(e)
#define LOG2E 1.4426950408889634f

typedef __attribute__((ext_vector_type(8))) short bf16x8;
typedef __attribute__((ext_vector_type(8))) _Float16 f16x8;
typedef __attribute__((ext_vector_type(2))) _Float16 f16x2;
typedef __attribute__((ext_vector_type(2))) __fp16 fp16x2;
typedef __attribute__((ext_vector_type(4))) float f32x4;
typedef __attribute__((ext_vector_type(16))) float f32x16;
typedef __attribute__((ext_vector_type(4))) unsigned short u16x4;
typedef __attribute__((ext_vector_type(4))) unsigned int u32x4;

__device__ __forceinline__ unsigned short f2bf(float f) {
  unsigned int u = __float_as_uint(f);
  u += 0x7fffu + ((u >> 16) & 1u);
  return (unsigned short)(u >> 16);
}

#define MFMA16(a, b, c)    __builtin_amdgcn_mfma_f32_16x16x32_bf16(a, b, c, 0, 0, 0)
#define MFMA32_BF(a, b, c) __builtin_amdgcn_mfma_f32_32x32x16_bf16(a, b, c, 0, 0, 0)
#define MFMA32_F16(a, b, c) __builtin_amdgcn_mfma_f32_32x32x16_f16(a, b, c, 0, 0, 0)

__device__ __forceinline__ void plswap(unsigned& a, unsigned& b) {
  asm volatile("v_permlane32_swap_b32 %0, %1" : "+v"(a), "+v"(b));
}

// cvt_pkrtz with __fp16->_Float16 vector reinterpret (bit-identical)
__device__ __forceinline__ f16x2 pkrtz(float a, float b) {
  union { fp16x2 p; f16x2 h; } cv;
  cv.p = __builtin_amdgcn_cvt_pkrtz(a, b);
  return cv.h;
}

// ---------------------------------------------------------------------------
// Projection GEMM: out[m][n] = (sum_k A[m][k]*W[n][k] + bias[n]) * out_scale
// OMODE: 0 = f32 flat [M][128]; 1 = bf16 split [B][h][tok][64]; 2 = f16 split.
// ---------------------------------------------------------------------------
template<bool IN_F32, int OMODE>
__global__ __launch_bounds__(256)
void proj_gemm(const void* __restrict__ Ain, const float* __restrict__ W,
               const float* __restrict__ bias, void* __restrict__ Out,
               float out_scale)
{
  __shared__ __align__(16) unsigned short xs[64][136];
  __shared__ __align__(16) unsigned short wsh[128][136];
  const int tid = threadIdx.x;
  const int m0 = blockIdx.x * 64;
  const int w = tid >> 6, l = tid & 63;
  const int lk = l & 15, lg = l >> 4;

  {
    const float4* Wv = (const float4*)W;
#pragma unroll
    for (int i = 0; i < 16; ++i) {
      int f = tid + i * 256;
      float4 v = Wv[f];
      int row = f >> 5, col = (f & 31) << 2;
      u16x4 pk = { f2bf(v.x), f2bf(v.y), f2bf(v.z), f2bf(v.w) };
      *(u16x4*)&wsh[row][col] = pk;
    }
  }
  if (IN_F32) {
    const float4* Xv = (const float4*)((const float*)Ain + (size_t)m0 * CDIM);
#pragma unroll
    for (int i = 0; i < 8; ++i) {
      int f = tid + i * 256;
      float4 v = Xv[f];
      int row = f >> 5, col = (f & 31) << 2;
      u16x4 pk = { f2bf(v.x), f2bf(v.y), f2bf(v.z), f2bf(v.w) };
      *(u16x4*)&xs[row][col] = pk;
    }
  } else {
    const bf16x8* Xv = (const bf16x8*)((const unsigned short*)Ain + (size_t)m0 * CDIM);
#pragma unroll
    for (int i = 0; i < 4; ++i) {
      int c = tid + i * 256;
      bf16x8 v = Xv[c];
      int row = c >> 4, col = (c & 15) << 3;
      *(bf16x8*)&xs[row][col] = v;
    }
  }
  __syncthreads();

  f32x4 acc[8];
#pragma unroll
  for (int nf = 0; nf < 8; ++nf) acc[nf] = (f32x4){0.f, 0.f, 0.f, 0.f};

#pragma unroll
  for (int kk = 0; kk < 4; ++kk) {
    bf16x8 a = *(const bf16x8*)&xs[w * 16 + lk][kk * 32 + 8 * lg];
#pragma unroll
    for (int nf = 0; nf < 8; ++nf) {
      bf16x8 b = *(const bf16x8*)&wsh[nf * 16 + lk][kk * 32 + 8 * lg];
      acc[nf] = MFMA16(a, b, acc[nf]);
    }
  }

#pragma unroll
  for (int reg = 0; reg < 4; ++reg) {
    int row = m0 + w * 16 + 4 * lg + reg;
    int bb = row / N_TOK;
    int tok = row - bb * N_TOK;
#pragma unroll
    for (int nf = 0; nf < 8; ++nf) {
      int col = nf * 16 + lk;
      float val = (acc[nf][reg] + bias[col]) * out_scale;
      if (OMODE == 0) {
        ((float*)Out)[(size_t)row * CDIM + col] = val;
      } else {
        int head = nf >> 2;
        int d = col & 63;
        size_t idx = ((size_t)(bb * NHEAD + head) * N_TOK + tok) * DH + d;
        if (OMODE == 1) ((unsigned short*)Out)[idx] = f2bf(val);
        else            ((unsigned short*)Out)[idx] = __half_as_ushort(__float2half(val));
      }
    }
  }
}

// ---------------------------------------------------------------------------
// Pre-kernel: E[h][kt][q][hi][ct][r] (f16) = exp(relpos[h][q][kt*64 + key])
// where key-in-tile = 32*ct + (r&3) + 8*(r>>2) + 4*hi  (matches attn32 lanes).
// ---------------------------------------------------------------------------
__global__ __launch_bounds__(256)
void exp_rp(const float* __restrict__ rp, __half* __restrict__ E)
{
  const int hkt = blockIdx.x;            // 0..97
  const int h = hkt / NT, kt = hkt % NT;
  const int q0 = blockIdx.y * 64;
  const int t = threadIdx.x;
  const int kp = t & 63;                 // key within tile
  const int qi = t >> 6;                 // 0..3

  const int ct = kp >> 5;
  const int kpp = kp & 31;
  const int hi = (kpp >> 2) & 1;
  const int r = (kpp & 3) + ((kpp >> 3) << 2);
  const int didx = hi * 32 + ct * 16 + r;

  const float* src = rp + ((size_t)h * N_TOK + q0) * N_TOK + kt * 64 + kp;
  __half* dst = E + (((size_t)h * NT + kt) * N_TOK + q0) * 64 + didx;

#pragma unroll
  for (int i = 0; i < 16; ++i) {
    int q = qi * 16 + i;
    float v = __expf(src[(size_t)q * N_TOK]);
    dst[(size_t)q * 64] = __float2half(v);
  }
}

// ---------------------------------------------------------------------------
// attn32: swapped-operand 32x32 flash attention, zero-LDS P path.
// WG = 4 waves x 32 q rows = 128 q. Grid (B, 25, NHEAD).
// LDS: Ks[64][72] bf16 (XOR-swizzled d-units), Vts[64][72] f16 (V^T,
// swizzled key-units); epilogue aliases as Ot[128][72] bf16.
// ---------------------------------------------------------------------------
__global__ __launch_bounds__(256)
void attn32(const unsigned short* __restrict__ q_ws,
            const unsigned short* __restrict__ k_ws,
            const unsigned short* __restrict__ v_ws,
            const __half* __restrict__ E,
            unsigned short* __restrict__ attn_out)
{
  __shared__ __align__(16) unsigned short LDSU[9216];
  unsigned short* Ks = LDSU;          // 64*72
  unsigned short* Vts = LDSU + 4608;  // 64*72

  const int b = blockIdx.x, qt = blockIdx.y, head = blockIdx.z;
  const int tid = threadIdx.x;
  const int w = tid >> 6, l = tid & 63;
  const int lq = l & 31, hi = l >> 5;
  const int swz = lq & 7;

  const size_t bh = ((size_t)b * NHEAD + head) * N_TOK;
  const unsigned short* Kp = k_ws + bh * DH;
  const _Float16* Vg = (const _Float16*)v_ws + bh * DH;

  int qg = qt * 128 + w * 32 + lq;
  if (qg > N_TOK - 1) qg = N_TOK - 1;

  // Q B-frags: qf[ks] holds Q[qg][16*ks + 8*hi + 0..7]
  bf16x8 qf[4];
  {
    const unsigned short* qrow = q_ws + (bh + (size_t)qg) * DH + 8 * hi;
#pragma unroll
    for (int ks = 0; ks < 4; ++ks) qf[ks] = *(const bf16x8*)(qrow + 16 * ks);
  }

  // K staging: thread t -> key = t>>3 (+32), d-unit = t&7, XOR-swizzled
  const int kr0 = tid >> 3, ku = tid & 7;
  const int kswz0 = kr0 * 72 + ((ku ^ (kr0 & 7)) << 3);
  const int kswz1 = (kr0 + 32) * 72 + ((ku ^ (kr0 & 7)) << 3);
  const int gk0 = kr0 * DH + ku * 8, gk1 = gk0 + 32 * DH;
  // V staging: key = t&63, d0 = (t>>6)*8 (+32), scatter-transpose
  const int vkey = tid & 63;
  const int vd0 = (tid >> 6) << 3;
  const int gv0 = vkey * DH + vd0, gv1 = gv0 + 32;
  const int vku = vkey >> 3, vke = vkey & 7;

  // E base for this lane (f16 units); per-tile stride N_TOK*64
  const __half* Eb = E + (((size_t)head * NT) * N_TOK + (size_t)qg) * 64 + hi * 32;

  float lsum = 0.f;
  f32x16 o0, o1;
#pragma unroll
  for (int i = 0; i < 16; ++i) { o0[i] = 0.f; o1[i] = 0.f; }

  // prefetch tile 0
  bf16x8 kpreA = *(const bf16x8*)(Kp + gk0);
  bf16x8 kpreB = *(const bf16x8*)(Kp + gk1);
  f16x8 vpreA = *(const f16x8*)(Vg + gv0);
  f16x8 vpreB = *(const f16x8*)(Vg + gv1);

  for (int kt = 0; kt < NT; ++kt) {
    asm volatile("s_waitcnt lgkmcnt(0)" ::: "memory");
    __builtin_amdgcn_s_barrier();          // A: tile kt-1 fully consumed
    asm volatile("" ::: "memory");

    *(bf16x8*)&Ks[kswz0] = kpreA;
    *(bf16x8*)&Ks[kswz1] = kpreB;
#pragma unroll
    for (int j = 0; j < 8; ++j) {
      int d = vd0 + j;
      int cu = ((vku ^ (d & 7)) << 3) + vke;
      Vts[d * 72 + cu] = ((const unsigned short*)&vpreA)[j];
      Vts[(d + 32) * 72 + cu] = ((const unsigned short*)&vpreB)[j];
    }

    // E loads for this tile: 4 x b128 (issued early, waited at use)
    u32x4 Ew[4];
    {
      const u32x4* ep = (const u32x4*)(Eb + (size_t)kt * (N_TOK * 64));
#pragma unroll
      for (int f = 0; f < 4; ++f) Ew[f] = ep[f];
    }

    if (kt + 1 < NT) {
      const unsigned short* kn = Kp + (size_t)(kt + 1) * 64 * DH;
      const _Float16* vn = Vg + (size_t)(kt + 1) * 64 * DH;
      kpreA = *(const bf16x8*)(kn + gk0);
      kpreB = *(const bf16x8*)(kn + gk1);
      vpreA = *(const f16x8*)(vn + gv0);
      vpreB = *(const f16x8*)(vn + gv1);
    }

    asm volatile("s_waitcnt lgkmcnt(0)" ::: "memory");
    __builtin_amdgcn_s_barrier();          // B: tile kt LDS visible
    asm volatile("" ::: "memory");

    // S^T = K_tile * Q^T : s{0,1}[reg] = S[key = 32*ct + (reg&3)+8*(reg>>2)+4*hi][q = lq]
    f32x16 s0, s1;
#pragma unroll
    for (int i = 0; i < 16; ++i) { s0[i] = 0.f; s1[i] = 0.f; }
#pragma unroll
    for (int ks = 0; ks < 4; ++ks) {
      bf16x8 kf0 = *(const bf16x8*)&Ks[lq * 72 + (((2 * ks + hi) ^ swz) << 3)];
      s0 = MFMA32_BF(kf0, qf[ks], s0);
      bf16x8 kf1 = *(const bf16x8*)&Ks[(32 + lq) * 72 + (((2 * ks + hi) ^ swz) << 3)];
      s1 = MFMA32_BF(kf1, qf[ks], s1);
    }

    // softmax (max-free) + f16 pack + permlane assembly of PV B-frags
    unsigned pw[16];
#pragma unroll
    for (int f = 0; f < 4; ++f) {
      int rb = (f & 1) * 8;
#pragma unroll
      for (int i = 0; i < 4; ++i) {
        float a = (f >> 1) ? s1[rb + 2 * i] : s0[rb + 2 * i];
        float c = (f >> 1) ? s1[rb + 2 * i + 1] : s0[rb + 2 * i + 1];
        f16x2 pp = pkrtz(__builtin_amdgcn_exp2f(a), __builtin_amdgcn_exp2f(c));
        union { unsigned u; f16x2 h; } ec; ec.u = Ew[f][i];
        f16x2 pr = pp * ec.h;
        lsum += (float)pr[0] + (float)pr[1];
        union { f16x2 h; unsigned u; } pu; pu.h = pr;
        pw[4 * f + i] = pu.u;
      }
      plswap(pw[4 * f + 0], pw[4 * f + 2]);
      plswap(pw[4 * f + 1], pw[4 * f + 3]);
    }

    // O^T += V^T * P^T
#pragma unroll
    for (int ks = 0; ks < 4; ++ks) {
      union { unsigned u[4]; f16x8 v; } pf;
#pragma unroll
      for (int i = 0; i < 4; ++i) pf.u[i] = pw[4 * ks + i];
      f16x8 vf0 = *(const f16x8*)&Vts[lq * 72 + (((2 * ks + hi) ^ swz) << 3)];
      o0 = MFMA32_F16(vf0, pf.v, o0);
      f16x8 vf1 = *(const f16x8*)&Vts[(32 + lq) * 72 + (((2 * ks + hi) ^ swz) << 3)];
      o1 = MFMA32_F16(vf1, pf.v, o1);
    }
  }

  // epilogue: complete row sums (other hi half), normalize, transpose via LDS
  lsum += __shfl_xor(lsum, 32, 64);
  float inv = 1.f / lsum;

  __syncthreads();
  unsigned short* Ot = LDSU;               // [128][72] bf16
  const int orow = (w * 32 + lq) * 72;
#pragma unroll
  for (int dt = 0; dt < 2; ++dt) {
#pragma unroll
    for (int j = 0; j < 8; ++j) {
      float v0 = (dt ? o1[2 * j] : o0[2 * j]) * inv;
      float v1 = (dt ? o1[2 * j + 1] : o0[2 * j + 1]) * inv;
      unsigned pk;
      asm("v_cvt_pk_bf16_f32 %0, %1, %2" : "=v"(pk) : "v"(v0), "v"(v1));
      int d = ((2 * j) & 3) + 8 * ((2 * j) >> 2) + 4 * hi + 32 * dt;
      *(unsigned*)&Ot[orow + d] = pk;
    }
  }
  __syncthreads();
#pragma unroll
  for (int i = 0; i < 4; ++i) {
    int c = tid + 256 * i;
    int ql = c >> 3, du = c & 7;
    int tok = qt * 128 + ql;
    if (tok < N_TOK) {
      u32x4 val = *(const u32x4*)&Ot[ql * 72 + du * 8];
      *(u32x4*)&attn_out[((size_t)b * N_TOK + tok) * CDIM + head * DH + du * 8] = val;
    }
  }
}

// ---------------------------------------------------------------------------
// Fallback attention (R3-proven, bf16 V, direct relpos) for small ws_size.
// ---------------------------------------------------------------------------
__global__ __launch_bounds__(256)
void attn_fallback(const unsigned short* __restrict__ q_ws,
                   const unsigned short* __restrict__ k_ws,
                   const unsigned short* __restrict__ v_ws,
                   const float* __restrict__ relpos,
                   unsigned short* __restrict__ attn_out)
{
  __shared__ __align__(16) unsigned short Ks[64][72];
  __shared__ __align__(16) unsigned short Vts[64][72];
  __shared__ __align__(16) unsigned short Ps[4][16][72];

  const int b = blockIdx.x, qt = blockIdx.y, head = blockIdx.z;
  const int tid = threadIdx.x;
  const int w = tid >> 6, l = tid & 63;
  const int lk = l & 15, lg = l >> 4;

  const size_t bh = ((size_t)b * NHEAD + head) * N_TOK;
  const unsigned short* Qp = q_ws + (bh + (size_t)qt * 64) * DH;
  const unsigned short* Kp = k_ws + bh * DH;
  const unsigned short* Vg = v_ws + bh * DH;

  bf16x8 qf0, qf1;
  {
    const unsigned short* qrow = Qp + (size_t)(w * 16 + lk) * DH + 8 * lg;
    qf0 = *(const bf16x8*)qrow;
    qf1 = *(const bf16x8*)(qrow + 32);
  }

  const int kr0 = tid >> 3;
  const int ku = (tid & 7) << 3;
  const int gk0 = kr0 * DH + ku;
  const int gk1 = gk0 + 32 * DH;
  const int vkey = tid & 63;
  const int vd0 = (tid >> 6) << 3;
  const int gv0 = vkey * DH + vd0;
  const int gv1 = gv0 + 32;

  const int qrow0 = qt * 64 + w * 16;
  const float* rpb = relpos + (size_t)head * N_TOK * N_TOK +
                     (size_t)(qrow0 + 4 * lg) * N_TOK + lk;

  float l_run[4] = {0.f, 0.f, 0.f, 0.f};
  f32x4 acc[4];
#pragma unroll
  for (int nf = 0; nf < 4; ++nf) acc[nf] = (f32x4){0.f, 0.f, 0.f, 0.f};

  bf16x8 kpreA = *(const bf16x8*)(Kp + gk0);
  bf16x8 kpreB = *(const bf16x8*)(Kp + gk1);
  bf16x8 vpreA = *(const bf16x8*)(Vg + gv0);
  bf16x8 vpreB = *(const bf16x8*)(Vg + gv1);

  for (int kt = 0; kt < NT; ++kt) {
    float rp[4][4];
#pragma unroll
    for (int r = 0; r < 4; ++r)
#pragma unroll
      for (int ct = 0; ct < 4; ++ct)
        rp[ct][r] = rpb[(size_t)r * N_TOK + kt * 64 + ct * 16];

    asm volatile("s_waitcnt lgkmcnt(0)" ::: "memory");
    __builtin_amdgcn_s_barrier();
    asm volatile("" ::: "memory");

    *(bf16x8*)&Ks[kr0][ku] = kpreA;
    *(bf16x8*)&Ks[kr0 + 32][ku] = kpreB;
#pragma unroll
    for (int j = 0; j < 8; ++j) Vts[vd0 + j][vkey] = ((const unsigned short*)&vpreA)[j];
#pragma unroll
    for (int j = 0; j < 8; ++j) Vts[vd0 + 32 + j][vkey] = ((const unsigned short*)&vpreB)[j];

    if (kt + 1 < NT) {
      const unsigned short* kn = Kp + (size_t)(kt + 1) * 64 * DH;
      const unsigned short* vn = Vg + (size_t)(kt + 1) * 64 * DH;
      kpreA = *(const bf16x8*)(kn + gk0);
      kpreB = *(const bf16x8*)(kn + gk1);
      vpreA = *(const bf16x8*)(vn + gv0);
      vpreB = *(const bf16x8*)(vn + gv1);
    }

    asm volatile("s_waitcnt lgkmcnt(0)" ::: "memory");
    __builtin_amdgcn_s_barrier();
    asm volatile("" ::: "memory");

    f32x4 s[4];
#pragma unroll
    for (int ct = 0; ct < 4; ++ct) s[ct] = (f32x4){0.f, 0.f, 0.f, 0.f};
#pragma unroll
    for (int ct = 0; ct < 4; ++ct) {
      bf16x8 kb0 = *(const bf16x8*)&Ks[ct * 16 + lk][8 * lg];
      s[ct] = MFMA16(qf0, kb0, s[ct]);
      bf16x8 kb1 = *(const bf16x8*)&Ks[ct * 16 + lk][32 + 8 * lg];
      s[ct] = MFMA16(qf1, kb1, s[ct]);
    }

#pragma unroll
    for (int ct = 0; ct < 4; ++ct) {
      float p0 = __builtin_amdgcn_exp2f(fmaf(rp[ct][0], LOG2E, s[ct][0]));
      float p1 = __builtin_amdgcn_exp2f(fmaf(rp[ct][1], LOG2E, s[ct][1]));
      float p2 = __builtin_amdgcn_exp2f(fmaf(rp[ct][2], LOG2E, s[ct][2]));
      float p3 = __builtin_amdgcn_exp2f(fmaf(rp[ct][3], LOG2E, s[ct][3]));
      l_run[0] += p0; l_run[1] += p1; l_run[2] += p2; l_run[3] += p3;
      Ps[w][4 * lg + 0][ct * 16 + lk] = f2bf(p0);
      Ps[w][4 * lg + 1][ct * 16 + lk] = f2bf(p1);
      Ps[w][4 * lg + 2][ct * 16 + lk] = f2bf(p2);
      Ps[w][4 * lg + 3][ct * 16 + lk] = f2bf(p3);
    }

    bf16x8 pa0 = *(const bf16x8*)&Ps[w][lk][8 * lg];
    bf16x8 pa1 = *(const bf16x8*)&Ps[w][lk][32 + 8 * lg];
#pragma unroll
    for (int nf = 0; nf < 4; ++nf) {
      bf16x8 vb0 = *(const bf16x8*)&Vts[nf * 16 + lk][8 * lg];
      acc[nf] = MFMA16(pa0, vb0, acc[nf]);
      bf16x8 vb1 = *(const bf16x8*)&Vts[nf * 16 + lk][32 + 8 * lg];
      acc[nf] = MFMA16(pa1, vb1, acc[nf]);
    }
  }

#pragma unroll
  for (int m = 1; m <= 8; m <<= 1)
#pragma unroll
    for (int r = 0; r < 4; ++r)
      l_run[r] += __shfl_xor(l_run[r], m, 64);

#pragma unroll
  for (int r = 0; r < 4; ++r) {
    int tok = qrow0 + 4 * lg + r;
    float inv = 1.f / l_run[r];
#pragma unroll
    for (int nf = 0; nf < 4; ++nf) {
      attn_out[((size_t)b * N_TOK + tok) * CDIM + head * DH + nf * 16 + lk] =
          f2bf(acc[nf][r] * inv);
    }
  }
}

// ---------------------------------------------------------------------------
extern "C" void kernel_launch(void* const* d_in, const int* in_sizes, int n_in,
                              void* d_out, int out_size, void* d_ws, size_t ws_size,
                              hipStream_t stream) {
  (void)in_sizes; (void)n_in; (void)out_size;
  const float* x      = (const float*)d_in[0];
  const float* relpos = (const float*)d_in[3];
  const float* Wq = (const float*)d_in[4];  const float* bq = (const float*)d_in[5];
  const float* Wk = (const float*)d_in[6];  const float* bk = (const float*)d_in[7];
  const float* Wv = (const float*)d_in[8];  const float* bv = (const float*)d_in[9];
  const float* Wp = (const float*)d_in[10]; const float* bp = (const float*)d_in[11];

  const size_t QKV_ELEMS = (size_t)BATCH * NHEAD * N_TOK * DH;       // 3,211,264
  const size_t E_ELEMS   = (size_t)NHEAD * NT * N_TOK * DH;          // 19,668,992
  unsigned short* q_ws  = (unsigned short*)d_ws;
  unsigned short* k_ws  = q_ws + QKV_ELEMS;
  unsigned short* v_ws  = k_ws + QKV_ELEMS;
  unsigned short* ao_ws = v_ws + QKV_ELEMS;            // [B][N][C] bf16
  __half* E_ws = (__half*)(ao_ws + QKV_ELEMS);

  const bool big = ws_size >= (4 * QKV_ELEMS + E_ELEMS) * sizeof(unsigned short);

  dim3 blk(256);
  const int MTILES = (BATCH * N_TOK) / 64;  // 392

  proj_gemm<true, 1><<<MTILES, blk, 0, stream>>>((const void*)x, Wq, bq, (void*)q_ws, QK_SCALE);
  proj_gemm<true, 1><<<MTILES, blk, 0, stream>>>((const void*)x, Wk, bk, (void*)k_ws, 1.f);
  if (big) {
    proj_gemm<true, 2><<<MTILES, blk, 0, stream>>>((const void*)x, Wv, bv, (void*)v_ws, 1.f);
    exp_rp<<<dim3(NHEAD * NT, N_TOK / 64), blk, 0, stream>>>(relpos, E_ws);
    attn32<<<dim3(BATCH, (N_TOK + 127) / 128, NHEAD), blk, 0, stream>>>(
        q_ws, k_ws, v_ws, E_ws, ao_ws);
  } else {
    proj_gemm<true, 1><<<MTILES, blk, 0, stream>>>((const void*)x, Wv, bv, (void*)v_ws, 1.f);
    attn_fallback<<<dim3(BATCH, N_TOK / 64, NHEAD), blk, 0, stream>>>(
        q_ws, k_ws, v_ws, relpos, ao_ws);
  }

  proj_gemm<false, 0><<<MTILES, blk, 0, stream>>>((const void*)ao_ws, Wp, bp, d_out, 1.f);
}

// Round 6
// 127.163 us; speedup vs baseline: 1.8632x; 1.1425x over previous
//
#include <hip/hip_runtime.h>
#include <hip/hip_fp16.h>

#define N_TOK 3136
#define DH 64
#define NHEAD 2
#define CDIM 128
#define BATCH 8
#define NT 49                      // kv tiles of 64
#define QK_SCALE 0.18033688011112f // 0.125 * log2(e)
#define LOG2E 1.4426950408889634f

typedef __attribute__((ext_vector_type(8))) short bf16x8;
typedef __attribute__((ext_vector_type(8))) _Float16 f16x8;
typedef __attribute__((ext_vector_type(2))) _Float16 f16x2;
typedef __attribute__((ext_vector_type(2))) __fp16 fp16x2;
typedef __attribute__((ext_vector_type(4))) float f32x4;
typedef __attribute__((ext_vector_type(16))) float f32x16;
typedef __attribute__((ext_vector_type(4))) unsigned short u16x4;
typedef __attribute__((ext_vector_type(4))) unsigned int u32x4;

__device__ __forceinline__ unsigned short f2bf(float f) {
  unsigned int u = __float_as_uint(f);
  u += 0x7fffu + ((u >> 16) & 1u);
  return (unsigned short)(u >> 16);
}

#define MFMA16(a, b, c)    __builtin_amdgcn_mfma_f32_16x16x32_bf16(a, b, c, 0, 0, 0)
#define MFMA32_BF(a, b, c) __builtin_amdgcn_mfma_f32_32x32x16_bf16(a, b, c, 0, 0, 0)
#define MFMA32_F16(a, b, c) __builtin_amdgcn_mfma_f32_32x32x16_f16(a, b, c, 0, 0, 0)

__device__ __forceinline__ void plswap(unsigned& a, unsigned& b) {
  asm volatile("v_permlane32_swap_b32 %0, %1" : "+v"(a), "+v"(b));
}

// cvt_pkrtz with __fp16->_Float16 vector reinterpret (bit-identical)
__device__ __forceinline__ f16x2 pkrtz(float a, float b) {
  union { fp16x2 p; f16x2 h; } cv;
  cv.p = __builtin_amdgcn_cvt_pkrtz(a, b);
  return cv.h;
}

// ---------------------------------------------------------------------------
// Projection GEMM: out[m][n] = (sum_k A[m][k]*W[n][k] + bias[n]) * out_scale
// OMODE: 0 = f32 flat [M][128]; 1 = bf16 split [B][h][tok][64]; 2 = f16 split.
// ---------------------------------------------------------------------------
template<bool IN_F32, int OMODE>
__global__ __launch_bounds__(256)
void proj_gemm(const void* __restrict__ Ain, const float* __restrict__ W,
               const float* __restrict__ bias, void* __restrict__ Out,
               float out_scale)
{
  __shared__ __align__(16) unsigned short xs[64][136];
  __shared__ __align__(16) unsigned short wsh[128][136];
  const int tid = threadIdx.x;
  const int m0 = blockIdx.x * 64;
  const int w = tid >> 6, l = tid & 63;
  const int lk = l & 15, lg = l >> 4;

  {
    const float4* Wv = (const float4*)W;
#pragma unroll
    for (int i = 0; i < 16; ++i) {
      int f = tid + i * 256;
      float4 v = Wv[f];
      int row = f >> 5, col = (f & 31) << 2;
      u16x4 pk = { f2bf(v.x), f2bf(v.y), f2bf(v.z), f2bf(v.w) };
      *(u16x4*)&wsh[row][col] = pk;
    }
  }
  if (IN_F32) {
    const float4* Xv = (const float4*)((const float*)Ain + (size_t)m0 * CDIM);
#pragma unroll
    for (int i = 0; i < 8; ++i) {
      int f = tid + i * 256;
      float4 v = Xv[f];
      int row = f >> 5, col = (f & 31) << 2;
      u16x4 pk = { f2bf(v.x), f2bf(v.y), f2bf(v.z), f2bf(v.w) };
      *(u16x4*)&xs[row][col] = pk;
    }
  } else {
    const bf16x8* Xv = (const bf16x8*)((const unsigned short*)Ain + (size_t)m0 * CDIM);
#pragma unroll
    for (int i = 0; i < 4; ++i) {
      int c = tid + i * 256;
      bf16x8 v = Xv[c];
      int row = c >> 4, col = (c & 15) << 3;
      *(bf16x8*)&xs[row][col] = v;
    }
  }
  __syncthreads();

  f32x4 acc[8];
#pragma unroll
  for (int nf = 0; nf < 8; ++nf) acc[nf] = (f32x4){0.f, 0.f, 0.f, 0.f};

#pragma unroll
  for (int kk = 0; kk < 4; ++kk) {
    bf16x8 a = *(const bf16x8*)&xs[w * 16 + lk][kk * 32 + 8 * lg];
#pragma unroll
    for (int nf = 0; nf < 8; ++nf) {
      bf16x8 b = *(const bf16x8*)&wsh[nf * 16 + lk][kk * 32 + 8 * lg];
      acc[nf] = MFMA16(a, b, acc[nf]);
    }
  }

#pragma unroll
  for (int reg = 0; reg < 4; ++reg) {
    int row = m0 + w * 16 + 4 * lg + reg;
    int bb = row / N_TOK;
    int tok = row - bb * N_TOK;
#pragma unroll
    for (int nf = 0; nf < 8; ++nf) {
      int col = nf * 16 + lk;
      float val = (acc[nf][reg] + bias[col]) * out_scale;
      if (OMODE == 0) {
        ((float*)Out)[(size_t)row * CDIM + col] = val;
      } else {
        int head = nf >> 2;
        int d = col & 63;
        size_t idx = ((size_t)(bb * NHEAD + head) * N_TOK + tok) * DH + d;
        if (OMODE == 1) ((unsigned short*)Out)[idx] = f2bf(val);
        else            ((unsigned short*)Out)[idx] = __half_as_ushort(__float2half(val));
      }
    }
  }
}

// ---------------------------------------------------------------------------
// Pre-kernel: E[h][kt][q][hi][ct][r] (f16) = exp(relpos[h][q][kt*64 + key])
// where key-in-tile = 32*ct + (r&3) + 8*(r>>2) + 4*hi  (matches attn32 lanes).
// ---------------------------------------------------------------------------
__global__ __launch_bounds__(256)
void exp_rp(const float* __restrict__ rp, __half* __restrict__ E)
{
  const int hkt = blockIdx.x;            // 0..97
  const int h = hkt / NT, kt = hkt % NT;
  const int q0 = blockIdx.y * 64;
  const int t = threadIdx.x;
  const int kp = t & 63;                 // key within tile
  const int qi = t >> 6;                 // 0..3

  const int ct = kp >> 5;
  const int kpp = kp & 31;
  const int hi = (kpp >> 2) & 1;
  const int r = (kpp & 3) + ((kpp >> 3) << 2);
  const int didx = hi * 32 + ct * 16 + r;

  const float* src = rp + ((size_t)h * N_TOK + q0) * N_TOK + kt * 64 + kp;
  __half* dst = E + (((size_t)h * NT + kt) * N_TOK + q0) * 64 + didx;

#pragma unroll
  for (int i = 0; i < 16; ++i) {
    int q = qi * 16 + i;
    float v = __expf(src[(size_t)q * N_TOK]);
    dst[(size_t)q * 64] = __float2half(v);
  }
}

// ---------------------------------------------------------------------------
// attn32: swapped-operand 32x32 flash attention, zero-LDS P path,
// double-buffered LDS (one barrier per tile), E prefetched one tile ahead.
// WG = 4 waves x 32 q rows = 128 q. Grid (B, 25, NHEAD).
// Per buffer: K[64 key][72] bf16 | V^T[64 d][72] f16 (both unswizzled:
// 144B rows => bank-group = row mod 8, conflict-free per 8-lane phase).
// ---------------------------------------------------------------------------
__global__ __launch_bounds__(256)
void attn32(const unsigned short* __restrict__ q_ws,
            const unsigned short* __restrict__ k_ws,
            const unsigned short* __restrict__ v_ws,
            const __half* __restrict__ E,
            unsigned short* __restrict__ attn_out)
{
  __shared__ __align__(16) unsigned short LDSU[2][9216]; // [buf][K 4608 | V 4608]

  const int b = blockIdx.x, qt = blockIdx.y, head = blockIdx.z;
  const int tid = threadIdx.x;
  const int w = tid >> 6, l = tid & 63;
  const int lq = l & 31, hi = l >> 5;

  const size_t bh = ((size_t)b * NHEAD + head) * N_TOK;
  const unsigned short* Kp = k_ws + bh * DH;
  const _Float16* Vg = (const _Float16*)v_ws + bh * DH;

  int qg = qt * 128 + w * 32 + lq;
  if (qg > N_TOK - 1) qg = N_TOK - 1;

  // Q B-frags: qf[ks] holds Q[qg][16*ks + 8*hi + 0..7]
  bf16x8 qf[4];
  {
    const unsigned short* qrow = q_ws + (bh + (size_t)qg) * DH + 8 * hi;
#pragma unroll
    for (int ks = 0; ks < 4; ++ks) qf[ks] = *(const bf16x8*)(qrow + 16 * ks);
  }

  // K staging: thread t -> key = t>>3 (+32), d-unit = t&7
  const int kr0 = tid >> 3, ku = tid & 7;
  const int kofs = kr0 * 72 + ku * 8;
  const int gk0 = kr0 * DH + ku * 8, gk1 = gk0 + 32 * DH;
  // V staging: key = t&63, d0 = (t>>6)*8 (+32), scatter-transpose
  const int vkey = tid & 63;
  const int vd0 = (tid >> 6) << 3;
  const int gv0 = vkey * DH + vd0, gv1 = gv0 + 32;

  // E base for this lane (f16 units); per-tile stride N_TOK*DH
  const __half* Eb = E + (((size_t)head * NT) * N_TOK + (size_t)qg) * DH + hi * 32;

  float lsum = 0.f;
  f32x16 o0, o1;
#pragma unroll
  for (int i = 0; i < 16; ++i) { o0[i] = 0.f; o1[i] = 0.f; }

  // ---- prologue: tile 0 ----
  bf16x8 kpreA = *(const bf16x8*)(Kp + gk0);
  bf16x8 kpreB = *(const bf16x8*)(Kp + gk1);
  f16x8 vpreA = *(const f16x8*)(Vg + gv0);
  f16x8 vpreB = *(const f16x8*)(Vg + gv1);

  u32x4 EwA[4], EwB[4];
  {
    const u32x4* ep = (const u32x4*)Eb;   // kt = 0
#pragma unroll
    for (int f = 0; f < 4; ++f) EwA[f] = ep[f];
  }

  // store tile 0 -> buf0
  *(bf16x8*)&LDSU[0][kofs] = kpreA;
  *(bf16x8*)&LDSU[0][kofs + 32 * 72] = kpreB;
#pragma unroll
  for (int j = 0; j < 8; ++j) {
    LDSU[0][4608 + (vd0 + j) * 72 + vkey]      = ((const unsigned short*)&vpreA)[j];
    LDSU[0][4608 + (vd0 + 32 + j) * 72 + vkey] = ((const unsigned short*)&vpreB)[j];
  }
  // issue tile 1
  {
    const unsigned short* kn = Kp + (size_t)64 * DH;
    const _Float16* vn = Vg + (size_t)64 * DH;
    kpreA = *(const bf16x8*)(kn + gk0);
    kpreB = *(const bf16x8*)(kn + gk1);
    vpreA = *(const f16x8*)(vn + gv0);
    vpreB = *(const f16x8*)(vn + gv1);
  }
  asm volatile("s_waitcnt lgkmcnt(0)" ::: "memory");
  __builtin_amdgcn_s_barrier();
  asm volatile("" ::: "memory");

#define ATTN_BODY(PH, KT, EW_CUR, EW_NXT, LAST)                               \
  {                                                                           \
    const unsigned short* Kb = &LDSU[PH][0];                                  \
    const unsigned short* Vb = &LDSU[PH][4608];                               \
    unsigned short* Kn = &LDSU[PH ^ 1][0];                                    \
    unsigned short* Vn = &LDSU[PH ^ 1][4608];                                 \
    if (!(LAST)) { /* issue E(kt+1) */                                        \
      const u32x4* ep = (const u32x4*)(Eb + (size_t)((KT) + 1) * (N_TOK * DH)); \
      _Pragma("unroll") for (int f = 0; f < 4; ++f) EW_NXT[f] = ep[f];        \
    }                                                                         \
    /* S^T = K * Q^T */                                                       \
    f32x16 s0, s1;                                                            \
    _Pragma("unroll") for (int i = 0; i < 16; ++i) { s0[i] = 0.f; s1[i] = 0.f; } \
    __builtin_amdgcn_s_setprio(1);                                            \
    _Pragma("unroll") for (int ks = 0; ks < 4; ++ks) {                        \
      bf16x8 kf0 = *(const bf16x8*)&Kb[lq * 72 + 16 * ks + 8 * hi];           \
      s0 = MFMA32_BF(kf0, qf[ks], s0);                                        \
      bf16x8 kf1 = *(const bf16x8*)&Kb[(32 + lq) * 72 + 16 * ks + 8 * hi];    \
      s1 = MFMA32_BF(kf1, qf[ks], s1);                                        \
    }                                                                         \
    __builtin_amdgcn_s_setprio(0);                                            \
    if (!(LAST)) { /* store tile kt+1 into other buf; issue kt+2 */           \
      *(bf16x8*)&Kn[kofs] = kpreA;                                            \
      *(bf16x8*)&Kn[kofs + 32 * 72] = kpreB;                                  \
      _Pragma("unroll") for (int j = 0; j < 8; ++j) {                         \
        Vn[(vd0 + j) * 72 + vkey]      = ((const unsigned short*)&vpreA)[j];  \
        Vn[(vd0 + 32 + j) * 72 + vkey] = ((const unsigned short*)&vpreB)[j];  \
      }                                                                       \
      if ((KT) + 2 < NT) {                                                    \
        const unsigned short* kn2 = Kp + (size_t)((KT) + 2) * 64 * DH;        \
        const _Float16* vn2 = Vg + (size_t)((KT) + 2) * 64 * DH;              \
        kpreA = *(const bf16x8*)(kn2 + gk0);                                  \
        kpreB = *(const bf16x8*)(kn2 + gk1);                                  \
        vpreA = *(const f16x8*)(vn2 + gv0);                                   \
        vpreB = *(const f16x8*)(vn2 + gv1);                                   \
      }                                                                       \
    }                                                                         \
    /* softmax (max-free) + f16 pack + permlane */                            \
    unsigned pw[16];                                                          \
    _Pragma("unroll") for (int f = 0; f < 4; ++f) {                           \
      int rb = (f & 1) * 8;                                                   \
      _Pragma("unroll") for (int i = 0; i < 4; ++i) {                         \
        float a = (f >> 1) ? s1[rb + 2 * i] : s0[rb + 2 * i];                 \
        float c = (f >> 1) ? s1[rb + 2 * i + 1] : s0[rb + 2 * i + 1];         \
        f16x2 pp = pkrtz(__builtin_amdgcn_exp2f(a), __builtin_amdgcn_exp2f(c)); \
        union { unsigned u; f16x2 h; } ec; ec.u = EW_CUR[f][i];               \
        f16x2 pr = pp * ec.h;                                                 \
        lsum += (float)pr[0] + (float)pr[1];                                  \
        union { f16x2 h; unsigned u; } pu; pu.h = pr;                         \
        pw[4 * f + i] = pu.u;                                                 \
      }                                                                       \
      plswap(pw[4 * f + 0], pw[4 * f + 2]);                                   \
      plswap(pw[4 * f + 1], pw[4 * f + 3]);                                   \
    }                                                                         \
    /* O^T += V^T * P^T */                                                    \
    __builtin_amdgcn_s_setprio(1);                                            \
    _Pragma("unroll") for (int ks = 0; ks < 4; ++ks) {                        \
      union { unsigned u[4]; f16x8 v; } pf;                                   \
      _Pragma("unroll") for (int i = 0; i < 4; ++i) pf.u[i] = pw[4 * ks + i]; \
      f16x8 vf0 = *(const f16x8*)&Vb[lq * 72 + 16 * ks + 8 * hi];             \
      o0 = MFMA32_F16(vf0, pf.v, o0);                                         \
      f16x8 vf1 = *(const f16x8*)&Vb[(32 + lq) * 72 + 16 * ks + 8 * hi];      \
      o1 = MFMA32_F16(vf1, pf.v, o1);                                         \
    }                                                                         \
    __builtin_amdgcn_s_setprio(0);                                            \
    if (!(LAST)) {                                                            \
      asm volatile("s_waitcnt lgkmcnt(0)" ::: "memory");                      \
      __builtin_amdgcn_s_barrier();                                           \
      asm volatile("" ::: "memory");                                          \
    }                                                                         \
  }

  for (int kt2 = 0; kt2 < (NT - 1) / 2; ++kt2) {
    int kt = 2 * kt2;
    ATTN_BODY(0, kt, EwA, EwB, false);
    ATTN_BODY(1, kt + 1, EwB, EwA, false);
  }
  ATTN_BODY(0, NT - 1, EwA, EwB, true);
#undef ATTN_BODY

  // epilogue: complete row sums (other hi half), normalize, transpose via LDS
  lsum += __shfl_xor(lsum, 32, 64);
  float inv = 1.f / lsum;

  __syncthreads();
  unsigned short* Ot = &LDSU[0][0];        // [128][72] bf16
  const int orow = (w * 32 + lq) * 72;
#pragma unroll
  for (int dt = 0; dt < 2; ++dt) {
#pragma unroll
    for (int j = 0; j < 8; ++j) {
      float v0 = (dt ? o1[2 * j] : o0[2 * j]) * inv;
      float v1 = (dt ? o1[2 * j + 1] : o0[2 * j + 1]) * inv;
      unsigned pk;
      asm("v_cvt_pk_bf16_f32 %0, %1, %2" : "=v"(pk) : "v"(v0), "v"(v1));
      int d = ((2 * j) & 3) + 8 * ((2 * j) >> 2) + 4 * hi + 32 * dt;
      *(unsigned*)&Ot[orow + d] = pk;
    }
  }
  __syncthreads();
#pragma unroll
  for (int i = 0; i < 4; ++i) {
    int c = tid + 256 * i;
    int ql = c >> 3, du = c & 7;
    int tok = qt * 128 + ql;
    if (tok < N_TOK) {
      u32x4 val = *(const u32x4*)&Ot[ql * 72 + du * 8];
      *(u32x4*)&attn_out[((size_t)b * N_TOK + tok) * CDIM + head * DH + du * 8] = val;
    }
  }
}

// ---------------------------------------------------------------------------
// Fallback attention (R3-proven, bf16 V, direct relpos) for small ws_size.
// ---------------------------------------------------------------------------
__global__ __launch_bounds__(256)
void attn_fallback(const unsigned short* __restrict__ q_ws,
                   const unsigned short* __restrict__ k_ws,
                   const unsigned short* __restrict__ v_ws,
                   const float* __restrict__ relpos,
                   unsigned short* __restrict__ attn_out)
{
  __shared__ __align__(16) unsigned short Ks[64][72];
  __shared__ __align__(16) unsigned short Vts[64][72];
  __shared__ __align__(16) unsigned short Ps[4][16][72];

  const int b = blockIdx.x, qt = blockIdx.y, head = blockIdx.z;
  const int tid = threadIdx.x;
  const int w = tid >> 6, l = tid & 63;
  const int lk = l & 15, lg = l >> 4;

  const size_t bh = ((size_t)b * NHEAD + head) * N_TOK;
  const unsigned short* Qp = q_ws + (bh + (size_t)qt * 64) * DH;
  const unsigned short* Kp = k_ws + bh * DH;
  const unsigned short* Vg = v_ws + bh * DH;

  bf16x8 qf0, qf1;
  {
    const unsigned short* qrow = Qp + (size_t)(w * 16 + lk) * DH + 8 * lg;
    qf0 = *(const bf16x8*)qrow;
    qf1 = *(const bf16x8*)(qrow + 32);
  }

  const int kr0 = tid >> 3;
  const int ku = (tid & 7) << 3;
  const int gk0 = kr0 * DH + ku;
  const int gk1 = gk0 + 32 * DH;
  const int vkey = tid & 63;
  const int vd0 = (tid >> 6) << 3;
  const int gv0 = vkey * DH + vd0;
  const int gv1 = gv0 + 32;

  const int qrow0 = qt * 64 + w * 16;
  const float* rpb = relpos + (size_t)head * N_TOK * N_TOK +
                     (size_t)(qrow0 + 4 * lg) * N_TOK + lk;

  float l_run[4] = {0.f, 0.f, 0.f, 0.f};
  f32x4 acc[4];
#pragma unroll
  for (int nf = 0; nf < 4; ++nf) acc[nf] = (f32x4){0.f, 0.f, 0.f, 0.f};

  bf16x8 kpreA = *(const bf16x8*)(Kp + gk0);
  bf16x8 kpreB = *(const bf16x8*)(Kp + gk1);
  bf16x8 vpreA = *(const bf16x8*)(Vg + gv0);
  bf16x8 vpreB = *(const bf16x8*)(Vg + gv1);

  for (int kt = 0; kt < NT; ++kt) {
    float rp[4][4];
#pragma unroll
    for (int r = 0; r < 4; ++r)
#pragma unroll
      for (int ct = 0; ct < 4; ++ct)
        rp[ct][r] = rpb[(size_t)r * N_TOK + kt * 64 + ct * 16];

    asm volatile("s_waitcnt lgkmcnt(0)" ::: "memory");
    __builtin_amdgcn_s_barrier();
    asm volatile("" ::: "memory");

    *(bf16x8*)&Ks[kr0][ku] = kpreA;
    *(bf16x8*)&Ks[kr0 + 32][ku] = kpreB;
#pragma unroll
    for (int j = 0; j < 8; ++j) Vts[vd0 + j][vkey] = ((const unsigned short*)&vpreA)[j];
#pragma unroll
    for (int j = 0; j < 8; ++j) Vts[vd0 + 32 + j][vkey] = ((const unsigned short*)&vpreB)[j];

    if (kt + 1 < NT) {
      const unsigned short* kn = Kp + (size_t)(kt + 1) * 64 * DH;
      const unsigned short* vn = Vg + (size_t)(kt + 1) * 64 * DH;
      kpreA = *(const bf16x8*)(kn + gk0);
      kpreB = *(const bf16x8*)(kn + gk1);
      vpreA = *(const bf16x8*)(vn + gv0);
      vpreB = *(const bf16x8*)(vn + gv1);
    }

    asm volatile("s_waitcnt lgkmcnt(0)" ::: "memory");
    __builtin_amdgcn_s_barrier();
    asm volatile("" ::: "memory");

    f32x4 s[4];
#pragma unroll
    for (int ct = 0; ct < 4; ++ct) s[ct] = (f32x4){0.f, 0.f, 0.f, 0.f};
#pragma unroll
    for (int ct = 0; ct < 4; ++ct) {
      bf16x8 kb0 = *(const bf16x8*)&Ks[ct * 16 + lk][8 * lg];
      s[ct] = MFMA16(qf0, kb0, s[ct]);
      bf16x8 kb1 = *(const bf16x8*)&Ks[ct * 16 + lk][32 + 8 * lg];
      s[ct] = MFMA16(qf1, kb1, s[ct]);
    }

#pragma unroll
    for (int ct = 0; ct < 4; ++ct) {
      float p0 = __builtin_amdgcn_exp2f(fmaf(rp[ct][0], LOG2E, s[ct][0]));
      float p1 = __builtin_amdgcn_exp2f(fmaf(rp[ct][1], LOG2E, s[ct][1]));
      float p2 = __builtin_amdgcn_exp2f(fmaf(rp[ct][2], LOG2E, s[ct][2]));
      float p3 = __builtin_amdgcn_exp2f(fmaf(rp[ct][3], LOG2E, s[ct][3]));
      l_run[0] += p0; l_run[1] += p1; l_run[2] += p2; l_run[3] += p3;
      Ps[w][4 * lg + 0][ct * 16 + lk] = f2bf(p0);
      Ps[w][4 * lg + 1][ct * 16 + lk] = f2bf(p1);
      Ps[w][4 * lg + 2][ct * 16 + lk] = f2bf(p2);
      Ps[w][4 * lg + 3][ct * 16 + lk] = f2bf(p3);
    }

    bf16x8 pa0 = *(const bf16x8*)&Ps[w][lk][8 * lg];
    bf16x8 pa1 = *(const bf16x8*)&Ps[w][lk][32 + 8 * lg];
#pragma unroll
    for (int nf = 0; nf < 4; ++nf) {
      bf16x8 vb0 = *(const bf16x8*)&Vts[nf * 16 + lk][8 * lg];
      acc[nf] = MFMA16(pa0, vb0, acc[nf]);
      bf16x8 vb1 = *(const bf16x8*)&Vts[nf * 16 + lk][32 + 8 * lg];
      acc[nf] = MFMA16(pa1, vb1, acc[nf]);
    }
  }

#pragma unroll
  for (int m = 1; m <= 8; m <<= 1)
#pragma unroll
    for (int r = 0; r < 4; ++r)
      l_run[r] += __shfl_xor(l_run[r], m, 64);

#pragma unroll
  for (int r = 0; r < 4; ++r) {
    int tok = qrow0 + 4 * lg + r;
    float inv = 1.f / l_run[r];
#pragma unroll
    for (int nf = 0; nf < 4; ++nf) {
      attn_out[((size_t)b * N_TOK + tok) * CDIM + head * DH + nf * 16 + lk] =
          f2bf(acc[nf][r] * inv);
    }
  }
}

// ---------------------------------------------------------------------------
extern "C" void kernel_launch(void* const* d_in, const int* in_sizes, int n_in,
                              void* d_out, int out_size, void* d_ws, size_t ws_size,
                              hipStream_t stream) {
  (void)in_sizes; (void)n_in; (void)out_size;
  const float* x      = (const float*)d_in[0];
  const float* relpos = (const float*)d_in[3];
  const float* Wq = (const float*)d_in[4];  const float* bq = (const float*)d_in[5];
  const float* Wk = (const float*)d_in[6];  const float* bk = (const float*)d_in[7];
  const float* Wv = (const float*)d_in[8];  const float* bv = (const float*)d_in[9];
  const float* Wp = (const float*)d_in[10]; const float* bp = (const float*)d_in[11];

  const size_t QKV_ELEMS = (size_t)BATCH * NHEAD * N_TOK * DH;       // 3,211,264
  const size_t E_ELEMS   = (size_t)NHEAD * NT * N_TOK * DH;          // 19,668,992
  unsigned short* q_ws  = (unsigned short*)d_ws;
  unsigned short* k_ws  = q_ws + QKV_ELEMS;
  unsigned short* v_ws  = k_ws + QKV_ELEMS;
  unsigned short* ao_ws = v_ws + QKV_ELEMS;            // [B][N][C] bf16
  __half* E_ws = (__half*)(ao_ws + QKV_ELEMS);

  const bool big = ws_size >= (4 * QKV_ELEMS + E_ELEMS) * sizeof(unsigned short);

  dim3 blk(256);
  const int MTILES = (BATCH * N_TOK) / 64;  // 392

  proj_gemm<true, 1><<<MTILES, blk, 0, stream>>>((const void*)x, Wq, bq, (void*)q_ws, QK_SCALE);
  proj_gemm<true, 1><<<MTILES, blk, 0, stream>>>((const void*)x, Wk, bk, (void*)k_ws, 1.f);
  if (big) {
    proj_gemm<true, 2><<<MTILES, blk, 0, stream>>>((const void*)x, Wv, bv, (void*)v_ws, 1.f);
    exp_rp<<<dim3(NHEAD * NT, N_TOK / 64), blk, 0, stream>>>(relpos, E_ws);
    attn32<<<dim3(BATCH, (N_TOK + 127) / 128, NHEAD), blk, 0, stream>>>(
        q_ws, k_ws, v_ws, E_ws, ao_ws);
  } else {
    proj_gemm<true, 1><<<MTILES, blk, 0, stream>>>((const void*)x, Wv, bv, (void*)v_ws, 1.f);
    attn_fallback<<<dim3(BATCH, N_TOK / 64, NHEAD), blk, 0, stream>>>(
        q_ws, k_ws, v_ws, relpos, ao_ws);
  }

  proj_gemm<false, 0><<<MTILES, blk, 0, stream>>>((const void*)ao_ws, Wp, bp, d_out, 1.f);
}

// Round 7
// 120.931 us; speedup vs baseline: 1.9592x; 1.0515x over previous
//
#include <hip/hip_runtime.h>
#include <hip/hip_fp16.h>

#define N_TOK 3136
#define DH 64
#define NHEAD 2
#define CDIM 128
#define BATCH 8
#define NT 49                      // kv tiles of 64
#define QK_SCALE 0.18033688011112f // 0.125 * log2(e)
#define LOG2E 1.4426950408889634f

typedef __attribute__((ext_vector_type(8))) short bf16x8;
typedef __attribute__((ext_vector_type(8))) _Float16 f16x8;
typedef __attribute__((ext_vector_type(2))) _Float16 f16x2;
typedef __attribute__((ext_vector_type(2))) __fp16 fp16x2;
typedef __attribute__((ext_vector_type(4))) float f32x4;
typedef __attribute__((ext_vector_type(16))) float f32x16;
typedef __attribute__((ext_vector_type(4))) unsigned short u16x4;
typedef __attribute__((ext_vector_type(4))) unsigned int u32x4;

__device__ __forceinline__ unsigned short f2bf(float f) {
  unsigned int u = __float_as_uint(f);
  u += 0x7fffu + ((u >> 16) & 1u);
  return (unsigned short)(u >> 16);
}

#define MFMA16(a, b, c)    __builtin_amdgcn_mfma_f32_16x16x32_bf16(a, b, c, 0, 0, 0)
#define MFMA32_BF(a, b, c) __builtin_amdgcn_mfma_f32_32x32x16_bf16(a, b, c, 0, 0, 0)
#define MFMA32_F16(a, b, c) __builtin_amdgcn_mfma_f32_32x32x16_f16(a, b, c, 0, 0, 0)

__device__ __forceinline__ void plswap(unsigned& a, unsigned& b) {
  asm volatile("v_permlane32_swap_b32 %0, %1" : "+v"(a), "+v"(b));
}

// cvt_pkrtz with __fp16->_Float16 vector reinterpret (bit-identical)
__device__ __forceinline__ f16x2 pkrtz(float a, float b) {
  union { fp16x2 p; f16x2 h; } cv;
  cv.p = __builtin_amdgcn_cvt_pkrtz(a, b);
  return cv.h;
}

__device__ __forceinline__ float dot2acc(f16x2 pr, float acc) {
#if __has_builtin(__builtin_amdgcn_fdot2)
  union { f16x2 h; fp16x2 p; } c; c.h = pr;
  fp16x2 ones = {(__fp16)1.0f, (__fp16)1.0f};
  return __builtin_amdgcn_fdot2(c.p, ones, acc, false);
#else
  return acc + (float)pr[0] + (float)pr[1];
#endif
}

// ---------------------------------------------------------------------------
// Shared GEMM helpers (64-row x-tile  x  128x128 W, MFMA 16x16x32)
// ---------------------------------------------------------------------------
__device__ __forceinline__ void stage_w(const float* __restrict__ W,
                                        unsigned short (*wsh)[136], int tid) {
  const float4* Wv4 = (const float4*)W;
#pragma unroll
  for (int i = 0; i < 16; ++i) {
    int f = tid + i * 256;
    float4 v = Wv4[f];
    int row = f >> 5, col = (f & 31) << 2;
    u16x4 pk = { f2bf(v.x), f2bf(v.y), f2bf(v.z), f2bf(v.w) };
    *(u16x4*)&wsh[row][col] = pk;
  }
}

__device__ __forceinline__ void mfma_block(const unsigned short (*xs)[136],
                                           const unsigned short (*wsh)[136],
                                           int w, int lk, int lg, f32x4* acc) {
#pragma unroll
  for (int nf = 0; nf < 8; ++nf) acc[nf] = (f32x4){0.f, 0.f, 0.f, 0.f};
#pragma unroll
  for (int kk = 0; kk < 4; ++kk) {
    bf16x8 a = *(const bf16x8*)&xs[w * 16 + lk][kk * 32 + 8 * lg];
#pragma unroll
    for (int nf = 0; nf < 8; ++nf) {
      bf16x8 b = *(const bf16x8*)&wsh[nf * 16 + lk][kk * 32 + 8 * lg];
      acc[nf] = MFMA16(a, b, acc[nf]);
    }
  }
}

// ---------------------------------------------------------------------------
// Fused QKV projection: stage x tile once; Q,K -> bf16 [b][h][tok][64]
// (Q pre-scaled by QK_SCALE); V -> f16 TRANSPOSED [b][h][d][tok].
// ---------------------------------------------------------------------------
__global__ __launch_bounds__(256)
void proj_qkv(const float* __restrict__ x,
              const float* __restrict__ Wq, const float* __restrict__ bq,
              const float* __restrict__ Wk, const float* __restrict__ bk,
              const float* __restrict__ Wv, const float* __restrict__ bv,
              unsigned short* __restrict__ qo, unsigned short* __restrict__ ko,
              unsigned short* __restrict__ vo)
{
  __shared__ __align__(16) unsigned short xs[64][136];
  __shared__ __align__(16) unsigned short wsh[128][136];
  const int tid = threadIdx.x;
  const int m0 = blockIdx.x * 64;
  const int w = tid >> 6, l = tid & 63;
  const int lk = l & 15, lg = l >> 4;

  // stage x tile (f32 -> bf16)
  {
    const float4* Xv = (const float4*)(x + (size_t)m0 * CDIM);
#pragma unroll
    for (int i = 0; i < 8; ++i) {
      int f = tid + i * 256;
      float4 v = Xv[f];
      int row = f >> 5, col = (f & 31) << 2;
      u16x4 pk = { f2bf(v.x), f2bf(v.y), f2bf(v.z), f2bf(v.w) };
      *(u16x4*)&xs[row][col] = pk;
    }
  }
  stage_w(Wq, wsh, tid);
  __syncthreads();

  f32x4 acc[8];

  // ---- Q ----
  mfma_block(xs, wsh, w, lk, lg, acc);
#pragma unroll
  for (int reg = 0; reg < 4; ++reg) {
    int row = m0 + w * 16 + 4 * lg + reg;
    int bb = row / N_TOK, tok = row - bb * N_TOK;
#pragma unroll
    for (int nf = 0; nf < 8; ++nf) {
      int col = nf * 16 + lk;
      float val = (acc[nf][reg] + bq[col]) * QK_SCALE;
      qo[((size_t)(bb * NHEAD + (nf >> 2)) * N_TOK + tok) * DH + (col & 63)] = f2bf(val);
    }
  }
  __syncthreads();

  // ---- K ----
  stage_w(Wk, wsh, tid);
  __syncthreads();
  mfma_block(xs, wsh, w, lk, lg, acc);
#pragma unroll
  for (int reg = 0; reg < 4; ++reg) {
    int row = m0 + w * 16 + 4 * lg + reg;
    int bb = row / N_TOK, tok = row - bb * N_TOK;
#pragma unroll
    for (int nf = 0; nf < 8; ++nf) {
      int col = nf * 16 + lk;
      float val = acc[nf][reg] + bk[col];
      ko[((size_t)(bb * NHEAD + (nf >> 2)) * N_TOK + tok) * DH + (col & 63)] = f2bf(val);
    }
  }
  __syncthreads();

  // ---- V (transposed f16: [b][h][d][tok]) ----
  stage_w(Wv, wsh, tid);
  __syncthreads();
  mfma_block(xs, wsh, w, lk, lg, acc);
#pragma unroll
  for (int reg = 0; reg < 4; ++reg) {
    int row = m0 + w * 16 + 4 * lg + reg;
    int bb = row / N_TOK, tok = row - bb * N_TOK;
#pragma unroll
    for (int nf = 0; nf < 8; ++nf) {
      int col = nf * 16 + lk;
      float val = acc[nf][reg] + bv[col];
      size_t idx = ((size_t)(bb * NHEAD + (nf >> 2)) * DH + (col & 63)) * N_TOK + tok;
      vo[idx] = __half_as_ushort(__float2half(val));
    }
  }
}

// ---------------------------------------------------------------------------
// Pre-kernel: E[h][kt][q][hi][ct][r] (f16) = exp(relpos[h][q][kt*64 + key])
// where key-in-tile = 32*ct + (r&3) + 8*(r>>2) + 4*hi  (matches attn32 lanes).
// ---------------------------------------------------------------------------
__global__ __launch_bounds__(256)
void exp_rp(const float* __restrict__ rp, __half* __restrict__ E)
{
  const int hkt = blockIdx.x;            // 0..97
  const int h = hkt / NT, kt = hkt % NT;
  const int q0 = blockIdx.y * 64;
  const int t = threadIdx.x;
  const int kp = t & 63;                 // key within tile
  const int qi = t >> 6;                 // 0..3

  const int ct = kp >> 5;
  const int kpp = kp & 31;
  const int hi = (kpp >> 2) & 1;
  const int r = (kpp & 3) + ((kpp >> 3) << 2);
  const int didx = hi * 32 + ct * 16 + r;

  const float* src = rp + ((size_t)h * N_TOK + q0) * N_TOK + kt * 64 + kp;
  __half* dst = E + (((size_t)h * NT + kt) * N_TOK + q0) * 64 + didx;

#pragma unroll
  for (int i = 0; i < 16; ++i) {
    int q = qi * 16 + i;
    float v = __expf(src[(size_t)q * N_TOK]);
    dst[(size_t)q * 64] = __float2half(v);
  }
}

// ---------------------------------------------------------------------------
// attn32: swapped-operand 32x32 flash attention, zero-LDS P path,
// double-buffered LDS (one barrier per tile), E prefetched one tile ahead,
// V pre-transposed in global so staging is pure b128 (same as K).
// WG = 4 waves x 32 q rows = 128 q. Grid (B, 25, NHEAD).
// Per buffer: K[64 key][72] bf16 | V^T[64 d][72] f16 (144B rows: verified
// conflict-free for both b128 staging writes and fragment reads).
// ---------------------------------------------------------------------------
__global__ __launch_bounds__(256)
void attn32(const unsigned short* __restrict__ q_ws,
            const unsigned short* __restrict__ k_ws,
            const unsigned short* __restrict__ v_ws,   // V^T [b][h][d][tok] f16
            const __half* __restrict__ E,
            unsigned short* __restrict__ attn_out)
{
  __shared__ __align__(16) unsigned short LDSU[2][9216]; // [buf][K 4608 | V 4608]

  const int b = blockIdx.x, qt = blockIdx.y, head = blockIdx.z;
  const int tid = threadIdx.x;
  const int w = tid >> 6, l = tid & 63;
  const int lq = l & 31, hi = l >> 5;

  const size_t bh = ((size_t)b * NHEAD + head) * N_TOK;
  const unsigned short* Kp = k_ws + bh * DH;
  const _Float16* Vt = (const _Float16*)v_ws + bh * DH;  // V^T base (same product)

  int qg = qt * 128 + w * 32 + lq;
  if (qg > N_TOK - 1) qg = N_TOK - 1;

  // Q B-frags: qf[ks] holds Q[qg][16*ks + 8*hi + 0..7]
  bf16x8 qf[4];
  {
    const unsigned short* qrow = q_ws + (bh + (size_t)qg) * DH + 8 * hi;
#pragma unroll
    for (int ks = 0; ks < 4; ++ks) qf[ks] = *(const bf16x8*)(qrow + 16 * ks);
  }

  // staging mapping (identical for K and V^T): row = tid>>3 (+32), unit = tid&7
  const int kr0 = tid >> 3, ku = tid & 7;
  const int kofs = kr0 * 72 + ku * 8;              // LDS ushort offset
  const int gk0 = kr0 * DH + ku * 8, gk1 = gk0 + 32 * DH;     // K global (row=key)
  const int gvt0 = kr0 * N_TOK + ku * 8, gvt1 = gvt0 + 32 * N_TOK; // V^T global (row=d)

  // E base for this lane (f16 units); per-tile stride N_TOK*DH
  const __half* Eb = E + (((size_t)head * NT) * N_TOK + (size_t)qg) * DH + hi * 32;

  float lsum = 0.f;
  f32x16 o0, o1;
#pragma unroll
  for (int i = 0; i < 16; ++i) { o0[i] = 0.f; o1[i] = 0.f; }

  // ---- prologue: tile 0 ----
  bf16x8 kpreA = *(const bf16x8*)(Kp + gk0);
  bf16x8 kpreB = *(const bf16x8*)(Kp + gk1);
  f16x8 vpreA = *(const f16x8*)(Vt + gvt0);
  f16x8 vpreB = *(const f16x8*)(Vt + gvt1);

  u32x4 EwA[4], EwB[4];
  {
    const u32x4* ep = (const u32x4*)Eb;   // kt = 0
#pragma unroll
    for (int f = 0; f < 4; ++f) EwA[f] = ep[f];
  }

  // store tile 0 -> buf0
  *(bf16x8*)&LDSU[0][kofs] = kpreA;
  *(bf16x8*)&LDSU[0][kofs + 32 * 72] = kpreB;
  *(f16x8*)&LDSU[0][4608 + kofs] = vpreA;
  *(f16x8*)&LDSU[0][4608 + kofs + 32 * 72] = vpreB;
  // issue tile 1
  {
    const unsigned short* kn = Kp + (size_t)64 * DH;
    const _Float16* vn = Vt + 64;
    kpreA = *(const bf16x8*)(kn + gk0);
    kpreB = *(const bf16x8*)(kn + gk1);
    vpreA = *(const f16x8*)(vn + gvt0);
    vpreB = *(const f16x8*)(vn + gvt1);
  }
  asm volatile("s_waitcnt lgkmcnt(0)" ::: "memory");
  __builtin_amdgcn_s_barrier();
  asm volatile("" ::: "memory");

#define ATTN_BODY(PH, KT, EW_CUR, EW_NXT, LAST)                               \
  {                                                                           \
    const unsigned short* Kb = &LDSU[PH][0];                                  \
    const unsigned short* Vb = &LDSU[PH][4608];                               \
    unsigned short* Kn = &LDSU[PH ^ 1][0];                                    \
    unsigned short* Vn = &LDSU[PH ^ 1][4608];                                 \
    if (!(LAST)) { /* issue E(kt+1) */                                        \
      const u32x4* ep = (const u32x4*)(Eb + (size_t)((KT) + 1) * (N_TOK * DH)); \
      _Pragma("unroll") for (int f = 0; f < 4; ++f) EW_NXT[f] = ep[f];        \
    }                                                                         \
    /* S^T = K * Q^T */                                                       \
    f32x16 s0, s1;                                                            \
    _Pragma("unroll") for (int i = 0; i < 16; ++i) { s0[i] = 0.f; s1[i] = 0.f; } \
    __builtin_amdgcn_s_setprio(1);                                            \
    _Pragma("unroll") for (int ks = 0; ks < 4; ++ks) {                        \
      bf16x8 kf0 = *(const bf16x8*)&Kb[lq * 72 + 16 * ks + 8 * hi];           \
      s0 = MFMA32_BF(kf0, qf[ks], s0);                                        \
      bf16x8 kf1 = *(const bf16x8*)&Kb[(32 + lq) * 72 + 16 * ks + 8 * hi];    \
      s1 = MFMA32_BF(kf1, qf[ks], s1);                                        \
    }                                                                         \
    __builtin_amdgcn_s_setprio(0);                                            \
    if (!(LAST)) { /* store tile kt+1 into other buf; issue kt+2 */           \
      *(bf16x8*)&Kn[kofs] = kpreA;                                            \
      *(bf16x8*)&Kn[kofs + 32 * 72] = kpreB;                                  \
      *(f16x8*)&Vn[kofs] = vpreA;                                             \
      *(f16x8*)&Vn[kofs + 32 * 72] = vpreB;                                   \
      if ((KT) + 2 < NT) {                                                    \
        const unsigned short* kn2 = Kp + (size_t)((KT) + 2) * 64 * DH;        \
        const _Float16* vn2 = Vt + (size_t)((KT) + 2) * 64;                   \
        kpreA = *(const bf16x8*)(kn2 + gk0);                                  \
        kpreB = *(const bf16x8*)(kn2 + gk1);                                  \
        vpreA = *(const f16x8*)(vn2 + gvt0);                                  \
        vpreB = *(const f16x8*)(vn2 + gvt1);                                  \
      }                                                                       \
    }                                                                         \
    /* softmax (max-free) + f16 pack + permlane */                            \
    unsigned pw[16];                                                          \
    _Pragma("unroll") for (int f = 0; f < 4; ++f) {                           \
      int rb = (f & 1) * 8;                                                   \
      _Pragma("unroll") for (int i = 0; i < 4; ++i) {                         \
        float a = (f >> 1) ? s1[rb + 2 * i] : s0[rb + 2 * i];                 \
        float c = (f >> 1) ? s1[rb + 2 * i + 1] : s0[rb + 2 * i + 1];         \
        f16x2 pp = pkrtz(__builtin_amdgcn_exp2f(a), __builtin_amdgcn_exp2f(c)); \
        union { unsigned u; f16x2 h; } ec; ec.u = EW_CUR[f][i];               \
        f16x2 pr = pp * ec.h;                                                 \
        lsum = dot2acc(pr, lsum);                                             \
        union { f16x2 h; unsigned u; } pu; pu.h = pr;                         \
        pw[4 * f + i] = pu.u;                                                 \
      }                                                                       \
      plswap(pw[4 * f + 0], pw[4 * f + 2]);                                   \
      plswap(pw[4 * f + 1], pw[4 * f + 3]);                                   \
    }                                                                         \
    /* O^T += V^T * P^T */                                                    \
    __builtin_amdgcn_s_setprio(1);                                            \
    _Pragma("unroll") for (int ks = 0; ks < 4; ++ks) {                        \
      union { unsigned u[4]; f16x8 v; } pf;                                   \
      _Pragma("unroll") for (int i = 0; i < 4; ++i) pf.u[i] = pw[4 * ks + i]; \
      f16x8 vf0 = *(const f16x8*)&Vb[lq * 72 + 16 * ks + 8 * hi];             \
      o0 = MFMA32_F16(vf0, pf.v, o0);                                         \
      f16x8 vf1 = *(const f16x8*)&Vb[(32 + lq) * 72 + 16 * ks + 8 * hi];      \
      o1 = MFMA32_F16(vf1, pf.v, o1);                                         \
    }                                                                         \
    __builtin_amdgcn_s_setprio(0);                                            \
    if (!(LAST)) {                                                            \
      asm volatile("s_waitcnt lgkmcnt(0)" ::: "memory");                      \
      __builtin_amdgcn_s_barrier();                                           \
      asm volatile("" ::: "memory");                                          \
    }                                                                         \
  }

  for (int kt2 = 0; kt2 < (NT - 1) / 2; ++kt2) {
    int kt = 2 * kt2;
    ATTN_BODY(0, kt, EwA, EwB, false);
    ATTN_BODY(1, kt + 1, EwB, EwA, false);
  }
  ATTN_BODY(0, NT - 1, EwA, EwB, true);
#undef ATTN_BODY

  // epilogue: complete row sums (other hi half), normalize, transpose via LDS
  lsum += __shfl_xor(lsum, 32, 64);
  float inv = 1.f / lsum;

  __syncthreads();
  unsigned short* Ot = &LDSU[0][0];        // [128][72] bf16
  const int orow = (w * 32 + lq) * 72;
#pragma unroll
  for (int dt = 0; dt < 2; ++dt) {
#pragma unroll
    for (int j = 0; j < 8; ++j) {
      float v0 = (dt ? o1[2 * j] : o0[2 * j]) * inv;
      float v1 = (dt ? o1[2 * j + 1] : o0[2 * j + 1]) * inv;
      unsigned pk;
      asm("v_cvt_pk_bf16_f32 %0, %1, %2" : "=v"(pk) : "v"(v0), "v"(v1));
      int d = ((2 * j) & 3) + 8 * ((2 * j) >> 2) + 4 * hi + 32 * dt;
      *(unsigned*)&Ot[orow + d] = pk;
    }
  }
  __syncthreads();
#pragma unroll
  for (int i = 0; i < 4; ++i) {
    int c = tid + 256 * i;
    int ql = c >> 3, du = c & 7;
    int tok = qt * 128 + ql;
    if (tok < N_TOK) {
      u32x4 val = *(const u32x4*)&Ot[ql * 72 + du * 8];
      *(u32x4*)&attn_out[((size_t)b * N_TOK + tok) * CDIM + head * DH + du * 8] = val;
    }
  }
}

// ---------------------------------------------------------------------------
// Final projection (f32 out) and fallback-path projection (bf16 split out).
// ---------------------------------------------------------------------------
template<bool IN_F32, int OMODE>
__global__ __launch_bounds__(256)
void proj_gemm(const void* __restrict__ Ain, const float* __restrict__ W,
               const float* __restrict__ bias, void* __restrict__ Out,
               float out_scale)
{
  __shared__ __align__(16) unsigned short xs[64][136];
  __shared__ __align__(16) unsigned short wsh[128][136];
  const int tid = threadIdx.x;
  const int m0 = blockIdx.x * 64;
  const int w = tid >> 6, l = tid & 63;
  const int lk = l & 15, lg = l >> 4;

  stage_w(W, wsh, tid);
  if (IN_F32) {
    const float4* Xv = (const float4*)((const float*)Ain + (size_t)m0 * CDIM);
#pragma unroll
    for (int i = 0; i < 8; ++i) {
      int f = tid + i * 256;
      float4 v = Xv[f];
      int row = f >> 5, col = (f & 31) << 2;
      u16x4 pk = { f2bf(v.x), f2bf(v.y), f2bf(v.z), f2bf(v.w) };
      *(u16x4*)&xs[row][col] = pk;
    }
  } else {
    const bf16x8* Xv = (const bf16x8*)((const unsigned short*)Ain + (size_t)m0 * CDIM);
#pragma unroll
    for (int i = 0; i < 4; ++i) {
      int c = tid + i * 256;
      bf16x8 v = Xv[c];
      int row = c >> 4, col = (c & 15) << 3;
      *(bf16x8*)&xs[row][col] = v;
    }
  }
  __syncthreads();

  f32x4 acc[8];
  mfma_block(xs, wsh, w, lk, lg, acc);

#pragma unroll
  for (int reg = 0; reg < 4; ++reg) {
    int row = m0 + w * 16 + 4 * lg + reg;
    int bb = row / N_TOK;
    int tok = row - bb * N_TOK;
#pragma unroll
    for (int nf = 0; nf < 8; ++nf) {
      int col = nf * 16 + lk;
      float val = (acc[nf][reg] + bias[col]) * out_scale;
      if (OMODE == 0) {
        ((float*)Out)[(size_t)row * CDIM + col] = val;
      } else {
        int head = nf >> 2;
        int d = col & 63;
        size_t idx = ((size_t)(bb * NHEAD + head) * N_TOK + tok) * DH + d;
        ((unsigned short*)Out)[idx] = f2bf(val);
      }
    }
  }
}

// ---------------------------------------------------------------------------
// Fallback attention (R3-proven, bf16 V row-major, direct relpos).
// ---------------------------------------------------------------------------
__global__ __launch_bounds__(256)
void attn_fallback(const unsigned short* __restrict__ q_ws,
                   const unsigned short* __restrict__ k_ws,
                   const unsigned short* __restrict__ v_ws,
                   const float* __restrict__ relpos,
                   unsigned short* __restrict__ attn_out)
{
  __shared__ __align__(16) unsigned short Ks[64][72];
  __shared__ __align__(16) unsigned short Vts[64][72];
  __shared__ __align__(16) unsigned short Ps[4][16][72];

  const int b = blockIdx.x, qt = blockIdx.y, head = blockIdx.z;
  const int tid = threadIdx.x;
  const int w = tid >> 6, l = tid & 63;
  const int lk = l & 15, lg = l >> 4;

  const size_t bh = ((size_t)b * NHEAD + head) * N_TOK;
  const unsigned short* Qp = q_ws + (bh + (size_t)qt * 64) * DH;
  const unsigned short* Kp = k_ws + bh * DH;
  const unsigned short* Vg = v_ws + bh * DH;

  bf16x8 qf0, qf1;
  {
    const unsigned short* qrow = Qp + (size_t)(w * 16 + lk) * DH + 8 * lg;
    qf0 = *(const bf16x8*)qrow;
    qf1 = *(const bf16x8*)(qrow + 32);
  }

  const int kr0 = tid >> 3;
  const int ku = (tid & 7) << 3;
  const int gk0 = kr0 * DH + ku;
  const int gk1 = gk0 + 32 * DH;
  const int vkey = tid & 63;
  const int vd0 = (tid >> 6) << 3;
  const int gv0 = vkey * DH + vd0;
  const int gv1 = gv0 + 32;

  const int qrow0 = qt * 64 + w * 16;
  const float* rpb = relpos + (size_t)head * N_TOK * N_TOK +
                     (size_t)(qrow0 + 4 * lg) * N_TOK + lk;

  float l_run[4] = {0.f, 0.f, 0.f, 0.f};
  f32x4 acc[4];
#pragma unroll
  for (int nf = 0; nf < 4; ++nf) acc[nf] = (f32x4){0.f, 0.f, 0.f, 0.f};

  bf16x8 kpreA = *(const bf16x8*)(Kp + gk0);
  bf16x8 kpreB = *(const bf16x8*)(Kp + gk1);
  bf16x8 vpreA = *(const bf16x8*)(Vg + gv0);
  bf16x8 vpreB = *(const bf16x8*)(Vg + gv1);

  for (int kt = 0; kt < NT; ++kt) {
    float rp[4][4];
#pragma unroll
    for (int r = 0; r < 4; ++r)
#pragma unroll
      for (int ct = 0; ct < 4; ++ct)
        rp[ct][r] = rpb[(size_t)r * N_TOK + kt * 64 + ct * 16];

    asm volatile("s_waitcnt lgkmcnt(0)" ::: "memory");
    __builtin_amdgcn_s_barrier();
    asm volatile("" ::: "memory");

    *(bf16x8*)&Ks[kr0][ku] = kpreA;
    *(bf16x8*)&Ks[kr0 + 32][ku] = kpreB;
#pragma unroll
    for (int j = 0; j < 8; ++j) Vts[vd0 + j][vkey] = ((const unsigned short*)&vpreA)[j];
#pragma unroll
    for (int j = 0; j < 8; ++j) Vts[vd0 + 32 + j][vkey] = ((const unsigned short*)&vpreB)[j];

    if (kt + 1 < NT) {
      const unsigned short* kn = Kp + (size_t)(kt + 1) * 64 * DH;
      const unsigned short* vn = Vg + (size_t)(kt + 1) * 64 * DH;
      kpreA = *(const bf16x8*)(kn + gk0);
      kpreB = *(const bf16x8*)(kn + gk1);
      vpreA = *(const bf16x8*)(vn + gv0);
      vpreB = *(const bf16x8*)(vn + gv1);
    }

    asm volatile("s_waitcnt lgkmcnt(0)" ::: "memory");
    __builtin_amdgcn_s_barrier();
    asm volatile("" ::: "memory");

    f32x4 s[4];
#pragma unroll
    for (int ct = 0; ct < 4; ++ct) s[ct] = (f32x4){0.f, 0.f, 0.f, 0.f};
#pragma unroll
    for (int ct = 0; ct < 4; ++ct) {
      bf16x8 kb0 = *(const bf16x8*)&Ks[ct * 16 + lk][8 * lg];
      s[ct] = MFMA16(qf0, kb0, s[ct]);
      bf16x8 kb1 = *(const bf16x8*)&Ks[ct * 16 + lk][32 + 8 * lg];
      s[ct] = MFMA16(qf1, kb1, s[ct]);
    }

#pragma unroll
    for (int ct = 0; ct < 4; ++ct) {
      float p0 = __builtin_amdgcn_exp2f(fmaf(rp[ct][0], LOG2E, s[ct][0]));
      float p1 = __builtin_amdgcn_exp2f(fmaf(rp[ct][1], LOG2E, s[ct][1]));
      float p2 = __builtin_amdgcn_exp2f(fmaf(rp[ct][2], LOG2E, s[ct][2]));
      float p3 = __builtin_amdgcn_exp2f(fmaf(rp[ct][3], LOG2E, s[ct][3]));
      l_run[0] += p0; l_run[1] += p1; l_run[2] += p2; l_run[3] += p3;
      Ps[w][4 * lg + 0][ct * 16 + lk] = f2bf(p0);
      Ps[w][4 * lg + 1][ct * 16 + lk] = f2bf(p1);
      Ps[w][4 * lg + 2][ct * 16 + lk] = f2bf(p2);
      Ps[w][4 * lg + 3][ct * 16 + lk] = f2bf(p3);
    }

    bf16x8 pa0 = *(const bf16x8*)&Ps[w][lk][8 * lg];
    bf16x8 pa1 = *(const bf16x8*)&Ps[w][lk][32 + 8 * lg];
#pragma unroll
    for (int nf = 0; nf < 4; ++nf) {
      bf16x8 vb0 = *(const bf16x8*)&Vts[nf * 16 + lk][8 * lg];
      acc[nf] = MFMA16(pa0, vb0, acc[nf]);
      bf16x8 vb1 = *(const bf16x8*)&Vts[nf * 16 + lk][32 + 8 * lg];
      acc[nf] = MFMA16(pa1, vb1, acc[nf]);
    }
  }

#pragma unroll
  for (int m = 1; m <= 8; m <<= 1)
#pragma unroll
    for (int r = 0; r < 4; ++r)
      l_run[r] += __shfl_xor(l_run[r], m, 64);

#pragma unroll
  for (int r = 0; r < 4; ++r) {
    int tok = qrow0 + 4 * lg + r;
    float inv = 1.f / l_run[r];
#pragma unroll
    for (int nf = 0; nf < 4; ++nf) {
      attn_out[((size_t)b * N_TOK + tok) * CDIM + head * DH + nf * 16 + lk] =
          f2bf(acc[nf][r] * inv);
    }
  }
}

// ---------------------------------------------------------------------------
extern "C" void kernel_launch(void* const* d_in, const int* in_sizes, int n_in,
                              void* d_out, int out_size, void* d_ws, size_t ws_size,
                              hipStream_t stream) {
  (void)in_sizes; (void)n_in; (void)out_size;
  const float* x      = (const float*)d_in[0];
  const float* relpos = (const float*)d_in[3];
  const float* Wq = (const float*)d_in[4];  const float* bq = (const float*)d_in[5];
  const float* Wk = (const float*)d_in[6];  const float* bk = (const float*)d_in[7];
  const float* Wv = (const float*)d_in[8];  const float* bv = (const float*)d_in[9];
  const float* Wp = (const float*)d_in[10]; const float* bp = (const float*)d_in[11];

  const size_t QKV_ELEMS = (size_t)BATCH * NHEAD * N_TOK * DH;       // 3,211,264
  const size_t E_ELEMS   = (size_t)NHEAD * NT * N_TOK * DH;          // 19,668,992
  unsigned short* q_ws  = (unsigned short*)d_ws;
  unsigned short* k_ws  = q_ws + QKV_ELEMS;
  unsigned short* v_ws  = k_ws + QKV_ELEMS;
  unsigned short* ao_ws = v_ws + QKV_ELEMS;            // [B][N][C] bf16
  __half* E_ws = (__half*)(ao_ws + QKV_ELEMS);

  const bool big = ws_size >= (4 * QKV_ELEMS + E_ELEMS) * sizeof(unsigned short);

  dim3 blk(256);
  const int MTILES = (BATCH * N_TOK) / 64;  // 392

  if (big) {
    proj_qkv<<<MTILES, blk, 0, stream>>>(x, Wq, bq, Wk, bk, Wv, bv, q_ws, k_ws, v_ws);
    exp_rp<<<dim3(NHEAD * NT, N_TOK / 64), blk, 0, stream>>>(relpos, E_ws);
    attn32<<<dim3(BATCH, (N_TOK + 127) / 128, NHEAD), blk, 0, stream>>>(
        q_ws, k_ws, v_ws, E_ws, ao_ws);
  } else {
    proj_gemm<true, 1><<<MTILES, blk, 0, stream>>>((const void*)x, Wq, bq, (void*)q_ws, QK_SCALE);
    proj_gemm<true, 1><<<MTILES, blk, 0, stream>>>((const void*)x, Wk, bk, (void*)k_ws, 1.f);
    proj_gemm<true, 1><<<MTILES, blk, 0, stream>>>((const void*)x, Wv, bv, (void*)v_ws, 1.f);
    attn_fallback<<<dim3(BATCH, N_TOK / 64, NHEAD), blk, 0, stream>>>(
        q_ws, k_ws, v_ws, relpos, ao_ws);
  }

  proj_gemm<false, 0><<<MTILES, blk, 0, stream>>>((const void*)ao_ws, Wp, bp, d_out, 1.f);
}